// Round 1
// baseline (2383.335 us; speedup 1.0000x reference)
//
#include <hip/hip_runtime.h>
#include <hip/hip_bf16.h>

using bf16   = __bf16;
using bf16x2 = __attribute__((ext_vector_type(2))) __bf16;
using bf16x4 = __attribute__((ext_vector_type(4))) __bf16;
using bf16x8 = __attribute__((ext_vector_type(8))) __bf16;
using f32x4  = __attribute__((ext_vector_type(4))) float;

constexpr int LAYERS = 4;
constexpr int BATCH  = 2;
constexpr int SEQ    = 1024;
constexpr int DIM    = 1024;
constexpr int FF     = 4096;
constexpr int HEADS  = 16;
constexpr int DHEAD  = 64;
constexpr int TOK    = BATCH * SEQ;   // 2048
constexpr float EPS  = 1e-5f;

// ---------------------------------------------------------------- LayerNorm
// x (f32 [TOK][DIM]) -> out (bf16 [TOK][DIM]); one block per row, 256 thr.
__global__ __launch_bounds__(256) void ln_kernel(
    const float* __restrict__ x, const float* __restrict__ g,
    const float* __restrict__ bt, bf16* __restrict__ out)
{
    __shared__ float red[8];
    const int row = blockIdx.x, t = threadIdx.x;
    const float4 v = ((const float4*)(x + (size_t)row * DIM))[t];

    float s = v.x + v.y + v.z + v.w;
    #pragma unroll
    for (int o = 32; o; o >>= 1) s += __shfl_down(s, o, 64);
    if ((t & 63) == 0) red[t >> 6] = s;
    __syncthreads();
    const float mean = (red[0] + red[1] + red[2] + red[3]) * (1.0f / DIM);

    const float dx = v.x - mean, dy = v.y - mean, dz = v.z - mean, dw = v.w - mean;
    float q = dx * dx + dy * dy + dz * dz + dw * dw;
    #pragma unroll
    for (int o = 32; o; o >>= 1) q += __shfl_down(q, o, 64);
    if ((t & 63) == 0) red[4 + (t >> 6)] = q;
    __syncthreads();
    const float var = (red[4] + red[5] + red[6] + red[7]) * (1.0f / DIM);
    const float rstd = rsqrtf(var + EPS);

    const float4 gg = ((const float4*)g)[t];
    const float4 bb = ((const float4*)bt)[t];
    bf16x4 o4;
    o4[0] = (bf16)(dx * rstd * gg.x + bb.x);
    o4[1] = (bf16)(dy * rstd * gg.y + bb.y);
    o4[2] = (bf16)(dz * rstd * gg.z + bb.z);
    o4[3] = (bf16)(dw * rstd * gg.w + bb.w);
    *(bf16x4*)(out + (size_t)row * DIM + t * 4) = o4;
}

// ---------------------------------------------------------------- GEMM
// C[M,N] = A[M,K](bf16) @ B[K,N](f32, converted to bf16 in staging)
// EPI 0: store bf16.  EPI 1: +bias, exact GELU, store bf16.
// EPI 2: +bias +resid(f32), store f32.
template<int EPI>
__global__ __launch_bounds__(256) void gemm_kernel(
    const bf16* __restrict__ A, const float* __restrict__ B,
    const float* __restrict__ bias, const float* __restrict__ resid,
    void* __restrict__ outv, int M, int N, int K)
{
    __shared__ bf16 As[128][40];   // padded: row stride 80 B (5x16B)
    __shared__ bf16 Bt[128][40];   // B tile stored transposed: [n][k]

    const int t    = threadIdx.x;
    const int lane = t & 63;
    const int w    = t >> 6;
    const int wm   = (w >> 1) * 64;
    const int wn   = (w & 1) * 64;
    const int bm   = blockIdx.x * 128;
    const int bn   = blockIdx.y * 128;
    const int kg   = lane >> 4;   // 0..3
    const int lr   = lane & 15;

    f32x4 acc[4][4] = {};

    const int rA = t >> 2, segA = t & 3;      // A stage: 2 rows x 16B each
    const int nB = t & 127, kqB = t >> 7;     // B stage: transpose

    for (int k0 = 0; k0 < K; k0 += 32) {
        // --- stage A (bf16, rows rA and rA+64, 16B each)
        uint4 va = *(const uint4*)(A + (size_t)(bm + rA) * K + k0 + segA * 8);
        uint4 vb = *(const uint4*)(A + (size_t)(bm + rA + 64) * K + k0 + segA * 8);
        *(uint4*)&As[rA][segA * 8]      = va;
        *(uint4*)&As[rA + 64][segA * 8] = vb;
        // --- stage B transposed (f32 -> bf16)
        #pragma unroll
        for (int it = 0; it < 4; ++it) {
            const int kk = (kqB + it * 2) * 4;           // k offset (0..28)
            const float* bp = B + (size_t)(k0 + kk) * N + bn + nB;
            bf16x4 pk;
            pk[0] = (bf16)bp[0];
            pk[1] = (bf16)bp[(size_t)N];
            pk[2] = (bf16)bp[2 * (size_t)N];
            pk[3] = (bf16)bp[3 * (size_t)N];
            *(bf16x4*)&Bt[nB][kk] = pk;
        }
        __syncthreads();

        bf16x8 af[4], bfr[4];
        #pragma unroll
        for (int m = 0; m < 4; ++m) af[m]  = *(const bf16x8*)&As[wm + m * 16 + lr][kg * 8];
        #pragma unroll
        for (int n = 0; n < 4; ++n) bfr[n] = *(const bf16x8*)&Bt[wn + n * 16 + lr][kg * 8];
        #pragma unroll
        for (int m = 0; m < 4; ++m)
            #pragma unroll
            for (int n = 0; n < 4; ++n)
                acc[m][n] = __builtin_amdgcn_mfma_f32_16x16x32_bf16(af[m], bfr[n], acc[m][n], 0, 0, 0);
        __syncthreads();
    }

    // --- epilogue: D row = wm+m*16+kg*4+j, col = wn+n*16+lr (verified layout)
    #pragma unroll
    for (int m = 0; m < 4; ++m) {
        const int row = bm + wm + m * 16 + kg * 4;
        #pragma unroll
        for (int n = 0; n < 4; ++n) {
            const int col = bn + wn + n * 16 + lr;
            #pragma unroll
            for (int j = 0; j < 4; ++j) {
                const float vv = acc[m][n][j];
                const size_t idx = (size_t)(row + j) * N + col;
                if (EPI == 0) {
                    ((bf16*)outv)[idx] = (bf16)vv;
                } else if (EPI == 1) {
                    const float z = vv + bias[col];
                    const float gl = 0.5f * z * (1.0f + erff(z * 0.70710678118654752f));
                    ((bf16*)outv)[idx] = (bf16)gl;
                } else {
                    ((float*)outv)[idx] = vv + bias[col] + resid[idx];
                }
            }
        }
    }
}

// ---------------------------------------------------------------- Attention
// q,k,v bf16 [TOK][DIM], heads = column blocks of 64. Block = (b,h,4 q rows).
__global__ __launch_bounds__(256) void attn_kernel(
    const bf16* __restrict__ qd, const bf16* __restrict__ kd,
    const bf16* __restrict__ vd, bf16* __restrict__ od)
{
    __shared__ float qs[4][64];
    __shared__ float sc[4][1024];
    __shared__ float red2[4][8][64];

    const int bh = blockIdx.y;            // 0..31
    const int b  = bh >> 4, h = bh & 15;
    const int q0 = blockIdx.x * 4;
    const int t  = threadIdx.x;
    const size_t base = (size_t)b * SEQ * DIM + h * DHEAD;

    {   // load 4 q rows into LDS as f32
        const int r = t >> 6, d = t & 63;
        qs[r][d] = (float)qd[base + (size_t)(q0 + r) * DIM + d];
    }
    __syncthreads();

    // ---- phase 1: scores for k rows {t, t+256, t+512, t+768}
    {
        float acc[4][4] = {};  // [ki][r]
        const bf16* kbase = kd + base;
        for (int d4 = 0; d4 < DHEAD; d4 += 8) {
            float qv[4][8];
            #pragma unroll
            for (int r = 0; r < 4; ++r)
                #pragma unroll
                for (int j = 0; j < 8; ++j) qv[r][j] = qs[r][d4 + j];
            #pragma unroll
            for (int i = 0; i < 4; ++i) {
                const bf16x8 kv = *(const bf16x8*)(kbase + (size_t)(t + i * 256) * DIM + d4);
                #pragma unroll
                for (int j = 0; j < 8; ++j) {
                    const float kf = (float)kv[j];
                    #pragma unroll
                    for (int r = 0; r < 4; ++r) acc[i][r] += qv[r][j] * kf;
                }
            }
        }
        #pragma unroll
        for (int i = 0; i < 4; ++i)
            #pragma unroll
            for (int r = 0; r < 4; ++r)
                sc[r][t + i * 256] = acc[i][r] * 0.125f;   // 1/sqrt(64)
    }
    __syncthreads();

    // ---- softmax: wave w owns row w
    {
        const int w = t >> 6, lane = t & 63;
        float m = -1e30f;
        for (int kk = lane; kk < SEQ; kk += 64) m = fmaxf(m, sc[w][kk]);
        #pragma unroll
        for (int o = 32; o; o >>= 1) m = fmaxf(m, __shfl_xor(m, o, 64));
        float s = 0.f;
        for (int kk = lane; kk < SEQ; kk += 64) {
            const float e = __expf(sc[w][kk] - m);
            sc[w][kk] = e; s += e;
        }
        #pragma unroll
        for (int o = 32; o; o >>= 1) s += __shfl_xor(s, o, 64);
        const float inv = 1.0f / s;
        for (int kk = lane; kk < SEQ; kk += 64) sc[w][kk] *= inv;
    }
    __syncthreads();

    // ---- phase 2: O[r][d] = sum_k p[r][k] * V[k][d]
    {
        const int dp = (t & 31) * 2, kc = t >> 5;   // 2 d-cols, 8 k-chunks of 128
        const bf16* vbase = vd + base;
        float oa[4][2] = {};
        for (int kk = kc * 128; kk < kc * 128 + 128; kk += 4) {
            f32x4 p[4];
            #pragma unroll
            for (int r = 0; r < 4; ++r) p[r] = *(const f32x4*)&sc[r][kk];
            #pragma unroll
            for (int u = 0; u < 4; ++u) {
                const bf16x2 vv = *(const bf16x2*)(vbase + (size_t)(kk + u) * DIM + dp);
                const float v0 = (float)vv[0], v1 = (float)vv[1];
                #pragma unroll
                for (int r = 0; r < 4; ++r) {
                    oa[r][0] += p[r][u] * v0;
                    oa[r][1] += p[r][u] * v1;
                }
            }
        }
        #pragma unroll
        for (int r = 0; r < 4; ++r) {
            red2[r][kc][dp]     = oa[r][0];
            red2[r][kc][dp + 1] = oa[r][1];
        }
    }
    __syncthreads();
    {
        const int r = t >> 6, dd = t & 63;
        float sum = 0.f;
        #pragma unroll
        for (int kc = 0; kc < 8; ++kc) sum += red2[r][kc][dd];
        od[base + (size_t)(q0 + r) * DIM + dd] = (bf16)sum;
    }
}

// ---------------------------------------------------------------- launch
extern "C" void kernel_launch(void* const* d_in, const int* in_sizes, int n_in,
                              void* d_out, int out_size, void* d_ws, size_t ws_size,
                              hipStream_t stream)
{
    const float* x    = (const float*)d_in[0];
    const float* ln1w = (const float*)d_in[1];
    const float* ln1b = (const float*)d_in[2];
    const float* Wq   = (const float*)d_in[3];
    const float* Wk   = (const float*)d_in[4];
    const float* Wv   = (const float*)d_in[5];
    const float* Wo   = (const float*)d_in[6];
    const float* bo   = (const float*)d_in[7];
    const float* ln2w = (const float*)d_in[8];
    const float* ln2b = (const float*)d_in[9];
    const float* W1   = (const float*)d_in[10];
    const float* b1   = (const float*)d_in[11];
    const float* W2   = (const float*)d_in[12];
    const float* b2   = (const float*)d_in[13];

    char* ws = (char*)d_ws;
    float* xbuf = (float*)ws;                               // 8 MB f32 residual
    bf16*  hbuf = (bf16*)(ws + (8  << 20));                 // 4 MB
    bf16*  qbuf = (bf16*)(ws + (12 << 20));                 // 4 MB
    bf16*  kbuf = (bf16*)(ws + (16 << 20));                 // 4 MB
    bf16*  vbuf = (bf16*)(ws + (20 << 20));                 // 4 MB
    bf16*  obuf = (bf16*)(ws + (24 << 20));                 // 4 MB
    bf16*  gbuf = (bf16*)(ws + (28 << 20));                 // 16 MB

    hipMemcpyAsync(xbuf, x, (size_t)TOK * DIM * sizeof(float),
                   hipMemcpyDeviceToDevice, stream);

    for (int l = 0; l < LAYERS; ++l) {
        const size_t dd = (size_t)l * DIM * DIM;
        const size_t df = (size_t)l * DIM * FF;

        ln_kernel<<<TOK, 256, 0, stream>>>(xbuf, ln1w + l * DIM, ln1b + l * DIM, hbuf);

        gemm_kernel<0><<<dim3(16, 8), 256, 0, stream>>>(hbuf, Wq + dd, nullptr, nullptr, qbuf, TOK, DIM, DIM);
        gemm_kernel<0><<<dim3(16, 8), 256, 0, stream>>>(hbuf, Wk + dd, nullptr, nullptr, kbuf, TOK, DIM, DIM);
        gemm_kernel<0><<<dim3(16, 8), 256, 0, stream>>>(hbuf, Wv + dd, nullptr, nullptr, vbuf, TOK, DIM, DIM);

        attn_kernel<<<dim3(SEQ / 4, BATCH * HEADS), 256, 0, stream>>>(qbuf, kbuf, vbuf, obuf);

        gemm_kernel<2><<<dim3(16, 8), 256, 0, stream>>>(obuf, Wo + dd, bo + l * DIM, xbuf, xbuf, TOK, DIM, DIM);

        ln_kernel<<<TOK, 256, 0, stream>>>(xbuf, ln2w + l * DIM, ln2b + l * DIM, hbuf);

        gemm_kernel<1><<<dim3(16, 32), 256, 0, stream>>>(hbuf, W1 + df, b1 + l * FF, nullptr, gbuf, TOK, FF, DIM);
        gemm_kernel<2><<<dim3(16, 8), 256, 0, stream>>>(gbuf, W2 + df, b2 + l * DIM, xbuf, xbuf, TOK, DIM, FF);
    }

    hipMemcpyAsync(d_out, xbuf, (size_t)TOK * DIM * sizeof(float),
                   hipMemcpyDeviceToDevice, stream);
}

// Round 2
// 901.506 us; speedup vs baseline: 2.6437x; 2.6437x over previous
//
#include <hip/hip_runtime.h>
#include <hip/hip_bf16.h>

using bf16   = __bf16;
using bf16x2 = __attribute__((ext_vector_type(2))) __bf16;
using bf16x4 = __attribute__((ext_vector_type(4))) __bf16;
using bf16x8 = __attribute__((ext_vector_type(8))) __bf16;
using f32x4  = __attribute__((ext_vector_type(4))) float;

constexpr int LAYERS = 4;
constexpr int BATCH  = 2;
constexpr int SEQ    = 1024;
constexpr int DIM    = 1024;
constexpr int FF     = 4096;
constexpr int HEADS  = 16;
constexpr int TOK    = BATCH * SEQ;   // 2048
constexpr int QKVN   = 3 * DIM;       // 3072
constexpr float EPS  = 1e-5f;

// async global->LDS, 16B per lane (HW: wave-uniform LDS base + lane*16)
__device__ __forceinline__ void gload_lds16(const void* g, void* l) {
    __builtin_amdgcn_global_load_lds(
        (const __attribute__((address_space(1))) void*)g,
        (__attribute__((address_space(3))) void*)l, 16, 0, 0);
}

// ---------------------------------------------------------------- LayerNorm
__global__ __launch_bounds__(256) void ln_kernel(
    const float* __restrict__ x, const float* __restrict__ g,
    const float* __restrict__ bt, bf16* __restrict__ out)
{
    __shared__ float red[8];
    const int row = blockIdx.x, t = threadIdx.x;
    const float4 v = ((const float4*)(x + (size_t)row * DIM))[t];

    float s = v.x + v.y + v.z + v.w;
    #pragma unroll
    for (int o = 32; o; o >>= 1) s += __shfl_down(s, o, 64);
    if ((t & 63) == 0) red[t >> 6] = s;
    __syncthreads();
    const float mean = (red[0] + red[1] + red[2] + red[3]) * (1.0f / DIM);

    const float dx = v.x - mean, dy = v.y - mean, dz = v.z - mean, dw = v.w - mean;
    float q = dx * dx + dy * dy + dz * dz + dw * dw;
    #pragma unroll
    for (int o = 32; o; o >>= 1) q += __shfl_down(q, o, 64);
    if ((t & 63) == 0) red[4 + (t >> 6)] = q;
    __syncthreads();
    const float var = (red[4] + red[5] + red[6] + red[7]) * (1.0f / DIM);
    const float rstd = rsqrtf(var + EPS);

    const float4 gg = ((const float4*)g)[t];
    const float4 bb = ((const float4*)bt)[t];
    bf16x4 o4;
    o4[0] = (bf16)(dx * rstd * gg.x + bb.x);
    o4[1] = (bf16)(dy * rstd * gg.y + bb.y);
    o4[2] = (bf16)(dz * rstd * gg.z + bb.z);
    o4[3] = (bf16)(dw * rstd * gg.w + bb.w);
    *(bf16x4*)(out + (size_t)row * DIM + t * 4) = o4;
}

// ------------------------------------------------- weight transpose+convert
// W f32 [K][N]  ->  Wt bf16 [rowoff + n][K]   (32x32 tiles via LDS)
__global__ __launch_bounds__(256) void wtrans_kernel(
    const float* __restrict__ W, bf16* __restrict__ Wt,
    int N, int K, int rowoff)
{
    __shared__ float tile[32][33];
    const int bn = blockIdx.x * 32, bk = blockIdx.y * 32;
    const int r = threadIdx.x >> 3, c4 = (threadIdx.x & 7) * 4;
    const float4 v = *(const float4*)(W + (size_t)(bk + r) * N + bn + c4);
    tile[r][c4 + 0] = v.x; tile[r][c4 + 1] = v.y;
    tile[r][c4 + 2] = v.z; tile[r][c4 + 3] = v.w;
    __syncthreads();
    bf16x4 o;
    #pragma unroll
    for (int j = 0; j < 4; ++j) o[j] = (bf16)tile[c4 + j][r];
    *(bf16x4*)(Wt + (size_t)(rowoff + bn + r) * K + bk + c4) = o;
}

// ---------------------------------------------------------------- GEMM
// C[M,N] = A[M,K](bf16) @ B (Bt = B^T, bf16 [N][K]).  BM=128, BK=32.
// EPI 0: bf16 store. 1: +bias, GELU, bf16. 2: +bias +resid(f32), f32.
template<int BN, int EPI>
__global__ __launch_bounds__(256) void gemm_kernel(
    const bf16* __restrict__ A, const bf16* __restrict__ Bt,
    const float* __restrict__ bias, const float* __restrict__ resid,
    void* __restrict__ outv, int M, int N, int K)
{
    constexpr int MR = (BN == 128) ? 4 : 2;
    __shared__ bf16 As[128 * 32];
    __shared__ bf16 Bs[BN * 32];

    const int t    = threadIdx.x;
    const int lane = t & 63;
    const int w    = t >> 6;
    const int wm   = (BN == 128) ? (w >> 1) * 64 : w * 32;
    const int wn   = (BN == 128) ? (w & 1) * 64 : 0;
    const int bm   = blockIdx.x * 128;
    const int bn   = blockIdx.y * BN;
    const int kg   = lane >> 4, lr = lane & 15;

    f32x4 acc[MR][4] = {};

    for (int k0 = 0; k0 < K; k0 += 32) {
        #pragma unroll
        for (int c = 0; c < 2; ++c) {
            const int ci = c * 256 + t;
            gload_lds16(A + (size_t)(bm + (ci >> 2)) * K + k0 + (ci & 3) * 8,
                        As + ci * 8);
        }
        #pragma unroll
        for (int c = 0; c < BN / 64; ++c) {
            const int ci = c * 256 + t;
            gload_lds16(Bt + (size_t)(bn + (ci >> 2)) * K + k0 + (ci & 3) * 8,
                        Bs + ci * 8);
        }
        __syncthreads();   // drains vmcnt before barrier -> LDS tile ready

        bf16x8 af[MR], bfr[4];
        #pragma unroll
        for (int m = 0; m < MR; ++m)
            af[m] = *(const bf16x8*)(As + (wm + m * 16 + lr) * 32 + kg * 8);
        #pragma unroll
        for (int n = 0; n < 4; ++n)
            bfr[n] = *(const bf16x8*)(Bs + (wn + n * 16 + lr) * 32 + kg * 8);
        #pragma unroll
        for (int m = 0; m < MR; ++m)
            #pragma unroll
            for (int n = 0; n < 4; ++n)
                acc[m][n] = __builtin_amdgcn_mfma_f32_16x16x32_bf16(af[m], bfr[n], acc[m][n], 0, 0, 0);
        __syncthreads();
    }

    // epilogue: D row = wm+m*16+kg*4+j, col = wn+n*16+lr
    #pragma unroll
    for (int m = 0; m < MR; ++m) {
        const int row = bm + wm + m * 16 + kg * 4;
        #pragma unroll
        for (int n = 0; n < 4; ++n) {
            const int col = bn + wn + n * 16 + lr;
            #pragma unroll
            for (int j = 0; j < 4; ++j) {
                const float vv = acc[m][n][j];
                const size_t idx = (size_t)(row + j) * N + col;
                if (EPI == 0) {
                    ((bf16*)outv)[idx] = (bf16)vv;
                } else if (EPI == 1) {
                    const float z = vv + bias[col];
                    const float gl = 0.5f * z * (1.0f + erff(z * 0.70710678118654752f));
                    ((bf16*)outv)[idx] = (bf16)gl;
                } else {
                    ((float*)outv)[idx] = vv + bias[col] + resid[idx];
                }
            }
        }
    }
}

// ------------------------------------------------- MFMA flash attention
// qkv bf16 [TOK][3072] (q|k|v); block = (b,h, 64 q rows), 4 waves x 16 rows.
__global__ __launch_bounds__(256) void attn_kernel(
    const bf16* __restrict__ qkv, bf16* __restrict__ od)
{
    __shared__ bf16 Ks[64][72];
    __shared__ bf16 Vt[64][72];   // [d][k]
    __shared__ bf16 Ps[64][72];   // wave-private rows

    const int bh = blockIdx.y;
    const int b  = bh >> 4, h = bh & 15;
    const int q0 = blockIdx.x * 64;
    const int t  = threadIdx.x, w = t >> 6, lane = t & 63;
    const int kg = lane >> 4, lr = lane & 15;

    const bf16* qbase = qkv + (size_t)b * SEQ * QKVN + h * 64;
    const bf16* kbase = qbase + DIM;
    const bf16* vbase = qbase + 2 * DIM;

    // Q fragments (wave's 16 rows, k = 0..63)
    bf16x8 qf0, qf1;
    {
        const bf16* qr = qbase + (size_t)(q0 + w * 16 + lr) * QKVN;
        qf0 = *(const bf16x8*)(qr + kg * 8);
        qf1 = *(const bf16x8*)(qr + 32 + kg * 8);
    }

    f32x4 o_acc[4] = {};
    float m_run[4] = {-1e30f, -1e30f, -1e30f, -1e30f};
    float l_run[4] = {};

    const int rK = t >> 3, oK = (t & 7) * 8;         // K stage: chunk 0
    const int rp = t >> 3, d0 = (t & 7) * 8;         // V transpose stage

    for (int kb = 0; kb < SEQ; kb += 64) {
        __syncthreads();   // previous tile fully consumed
        // ---- stage K rows (row-major)
        *(bf16x8*)&Ks[rK][oK] =
            *(const bf16x8*)(kbase + (size_t)(kb + rK) * QKVN + oK);
        *(bf16x8*)&Ks[32 + rK][oK] =
            *(const bf16x8*)(kbase + (size_t)(kb + 32 + rK) * QKVN + oK);
        // ---- stage V transposed: rows (2rp, 2rp+1), 8 d each -> bf16x2
        {
            const bf16x8 v0 = *(const bf16x8*)(vbase + (size_t)(kb + 2 * rp) * QKVN + d0);
            const bf16x8 v1 = *(const bf16x8*)(vbase + (size_t)(kb + 2 * rp + 1) * QKVN + d0);
            #pragma unroll
            for (int j = 0; j < 8; ++j) {
                bf16x2 p; p[0] = v0[j]; p[1] = v1[j];
                *(bf16x2*)&Vt[d0 + j][2 * rp] = p;
            }
        }
        __syncthreads();

        // ---- QK^T: scores 16 x 64 per wave
        f32x4 s[4] = {};
        #pragma unroll
        for (int n = 0; n < 4; ++n) {
            const bf16x8 kf0 = *(const bf16x8*)&Ks[n * 16 + lr][kg * 8];
            const bf16x8 kf1 = *(const bf16x8*)&Ks[n * 16 + lr][32 + kg * 8];
            s[n] = __builtin_amdgcn_mfma_f32_16x16x32_bf16(qf0, kf0, s[n], 0, 0, 0);
            s[n] = __builtin_amdgcn_mfma_f32_16x16x32_bf16(qf1, kf1, s[n], 0, 0, 0);
        }
        #pragma unroll
        for (int n = 0; n < 4; ++n) s[n] *= 0.125f;   // 1/sqrt(64)

        // ---- online softmax (row j of lane group; cols = 4 regs x 16 lanes)
        float corr[4], rs[4];
        #pragma unroll
        for (int j = 0; j < 4; ++j) {
            float mx = fmaxf(fmaxf(s[0][j], s[1][j]), fmaxf(s[2][j], s[3][j]));
            #pragma unroll
            for (int o = 1; o < 16; o <<= 1) mx = fmaxf(mx, __shfl_xor(mx, o, 64));
            const float mn = fmaxf(m_run[j], mx);
            corr[j] = __expf(m_run[j] - mn);
            m_run[j] = mn;
            rs[j] = 0.f;
        }
        #pragma unroll
        for (int n = 0; n < 4; ++n)
            #pragma unroll
            for (int j = 0; j < 4; ++j) {
                const float e = __expf(s[n][j] - m_run[j]);
                s[n][j] = e; rs[j] += e;
            }
        #pragma unroll
        for (int j = 0; j < 4; ++j) {
            #pragma unroll
            for (int o = 1; o < 16; o <<= 1) rs[j] += __shfl_xor(rs[j], o, 64);
            l_run[j] = l_run[j] * corr[j] + rs[j];
        }
        #pragma unroll
        for (int nd = 0; nd < 4; ++nd)
            #pragma unroll
            for (int j = 0; j < 4; ++j) o_acc[nd][j] *= corr[j];

        // ---- P -> LDS (wave-private rows), then PV
        #pragma unroll
        for (int n = 0; n < 4; ++n)
            #pragma unroll
            for (int j = 0; j < 4; ++j)
                Ps[w * 16 + kg * 4 + j][n * 16 + lr] = (bf16)s[n][j];

        const bf16x8 pf0 = *(const bf16x8*)&Ps[w * 16 + lr][kg * 8];
        const bf16x8 pf1 = *(const bf16x8*)&Ps[w * 16 + lr][32 + kg * 8];
        #pragma unroll
        for (int nd = 0; nd < 4; ++nd) {
            const bf16x8 vf0 = *(const bf16x8*)&Vt[nd * 16 + lr][kg * 8];
            const bf16x8 vf1 = *(const bf16x8*)&Vt[nd * 16 + lr][32 + kg * 8];
            o_acc[nd] = __builtin_amdgcn_mfma_f32_16x16x32_bf16(pf0, vf0, o_acc[nd], 0, 0, 0);
            o_acc[nd] = __builtin_amdgcn_mfma_f32_16x16x32_bf16(pf1, vf1, o_acc[nd], 0, 0, 0);
        }
    }

    // ---- finalize: O /= l, store
    float inv[4];
    #pragma unroll
    for (int j = 0; j < 4; ++j) inv[j] = 1.0f / l_run[j];
    bf16* ob = od + (size_t)(b * SEQ + q0 + w * 16 + kg * 4) * DIM + h * 64;
    #pragma unroll
    for (int nd = 0; nd < 4; ++nd)
        #pragma unroll
        for (int j = 0; j < 4; ++j)
            ob[(size_t)j * DIM + nd * 16 + lr] = (bf16)(o_acc[nd][j] * inv[j]);
}

// ---------------------------------------------------------------- launch
extern "C" void kernel_launch(void* const* d_in, const int* in_sizes, int n_in,
                              void* d_out, int out_size, void* d_ws, size_t ws_size,
                              hipStream_t stream)
{
    const float* x    = (const float*)d_in[0];
    const float* ln1w = (const float*)d_in[1];
    const float* ln1b = (const float*)d_in[2];
    const float* Wq   = (const float*)d_in[3];
    const float* Wk   = (const float*)d_in[4];
    const float* Wv   = (const float*)d_in[5];
    const float* Wo   = (const float*)d_in[6];
    const float* bo   = (const float*)d_in[7];
    const float* ln2w = (const float*)d_in[8];
    const float* ln2b = (const float*)d_in[9];
    const float* W1   = (const float*)d_in[10];
    const float* b1   = (const float*)d_in[11];
    const float* W2   = (const float*)d_in[12];
    const float* b2   = (const float*)d_in[13];

    char* ws = (char*)d_ws;
    float* xbuf  = (float*)(ws);                 // 8 MB
    bf16*  hbuf  = (bf16*)(ws + (8ull  << 20));  // 4 MB
    bf16*  qkvb  = (bf16*)(ws + (12ull << 20));  // 12 MB
    bf16*  obuf  = (bf16*)(ws + (24ull << 20));  // 4 MB
    bf16*  gbuf  = (bf16*)(ws + (28ull << 20));  // 16 MB
    bf16*  wqkvt = (bf16*)(ws + (44ull << 20));  // 6 MB  [3072][1024]
    bf16*  wot   = (bf16*)(ws + (50ull << 20));  // 2 MB  [1024][1024]
    bf16*  w1t   = (bf16*)(ws + (52ull << 20));  // 8 MB  [4096][1024]
    bf16*  w2t   = (bf16*)(ws + (60ull << 20));  // 8 MB  [1024][4096]

    hipMemcpyAsync(xbuf, x, (size_t)TOK * DIM * sizeof(float),
                   hipMemcpyDeviceToDevice, stream);

    const size_t DD = (size_t)DIM * DIM, DF = (size_t)DIM * FF;
    for (int l = 0; l < LAYERS; ++l) {
        // weight prep (bf16, transposed)
        wtrans_kernel<<<dim3(32, 32), 256, 0, stream>>>(Wq + l * DD, wqkvt, DIM, DIM, 0);
        wtrans_kernel<<<dim3(32, 32), 256, 0, stream>>>(Wk + l * DD, wqkvt, DIM, DIM, DIM);
        wtrans_kernel<<<dim3(32, 32), 256, 0, stream>>>(Wv + l * DD, wqkvt, DIM, DIM, 2 * DIM);
        wtrans_kernel<<<dim3(32, 32), 256, 0, stream>>>(Wo + l * DD, wot, DIM, DIM, 0);
        wtrans_kernel<<<dim3(128, 32), 256, 0, stream>>>(W1 + l * DF, w1t, FF, DIM, 0);
        wtrans_kernel<<<dim3(32, 128), 256, 0, stream>>>(W2 + l * DF, w2t, DIM, FF, 0);

        ln_kernel<<<TOK, 256, 0, stream>>>(xbuf, ln1w + l * DIM, ln1b + l * DIM, hbuf);

        gemm_kernel<128, 0><<<dim3(16, 24), 256, 0, stream>>>(
            hbuf, wqkvt, nullptr, nullptr, qkvb, TOK, QKVN, DIM);

        attn_kernel<<<dim3(SEQ / 64, BATCH * HEADS), 256, 0, stream>>>(qkvb, obuf);

        gemm_kernel<64, 2><<<dim3(16, 16), 256, 0, stream>>>(
            obuf, wot, bo + l * DIM, xbuf, xbuf, TOK, DIM, DIM);

        ln_kernel<<<TOK, 256, 0, stream>>>(xbuf, ln2w + l * DIM, ln2b + l * DIM, hbuf);

        gemm_kernel<128, 1><<<dim3(16, 32), 256, 0, stream>>>(
            hbuf, w1t, b1 + l * FF, nullptr, gbuf, TOK, FF, DIM);

        gemm_kernel<64, 2><<<dim3(16, 16), 256, 0, stream>>>(
            gbuf, w2t, b2 + l * DIM, xbuf, xbuf, TOK, DIM, FF);
    }

    hipMemcpyAsync(d_out, xbuf, (size_t)TOK * DIM * sizeof(float),
                   hipMemcpyDeviceToDevice, stream);
}

// Round 3
// 880.360 us; speedup vs baseline: 2.7072x; 1.0240x over previous
//
#include <hip/hip_runtime.h>
#include <hip/hip_bf16.h>

using bf16   = __bf16;
using bf16x2 = __attribute__((ext_vector_type(2))) __bf16;
using bf16x4 = __attribute__((ext_vector_type(4))) __bf16;
using bf16x8 = __attribute__((ext_vector_type(8))) __bf16;
using f32x4  = __attribute__((ext_vector_type(4))) float;

constexpr int LAYERS = 4;
constexpr int BATCH  = 2;
constexpr int SEQ    = 1024;
constexpr int DIM    = 1024;
constexpr int FF     = 4096;
constexpr int HEADS  = 16;
constexpr int TOK    = BATCH * SEQ;   // 2048
constexpr int QKVN   = 3 * DIM;       // 3072
constexpr float EPS  = 1e-5f;

// async global->LDS, 16B per lane (HW: wave-uniform LDS base + lane*16)
__device__ __forceinline__ void gload_lds16(const void* g, void* l) {
    __builtin_amdgcn_global_load_lds(
        (const __attribute__((address_space(1))) void*)g,
        (__attribute__((address_space(3))) void*)l, 16, 0, 0);
}

// ---------------------------------------------------------------- LayerNorm
__global__ __launch_bounds__(256) void ln_kernel(
    const float* __restrict__ x, const float* __restrict__ g,
    const float* __restrict__ bt, bf16* __restrict__ out)
{
    __shared__ float red[8];
    const int row = blockIdx.x, t = threadIdx.x;
    const float4 v = ((const float4*)(x + (size_t)row * DIM))[t];

    float s = v.x + v.y + v.z + v.w;
    #pragma unroll
    for (int o = 32; o; o >>= 1) s += __shfl_down(s, o, 64);
    if ((t & 63) == 0) red[t >> 6] = s;
    __syncthreads();
    const float mean = (red[0] + red[1] + red[2] + red[3]) * (1.0f / DIM);

    const float dx = v.x - mean, dy = v.y - mean, dz = v.z - mean, dw = v.w - mean;
    float q = dx * dx + dy * dy + dz * dz + dw * dw;
    #pragma unroll
    for (int o = 32; o; o >>= 1) q += __shfl_down(q, o, 64);
    if ((t & 63) == 0) red[4 + (t >> 6)] = q;
    __syncthreads();
    const float var = (red[4] + red[5] + red[6] + red[7]) * (1.0f / DIM);
    const float rstd = rsqrtf(var + EPS);

    const float4 gg = ((const float4*)g)[t];
    const float4 bb = ((const float4*)bt)[t];
    bf16x4 o4;
    o4[0] = (bf16)(dx * rstd * gg.x + bb.x);
    o4[1] = (bf16)(dy * rstd * gg.y + bb.y);
    o4[2] = (bf16)(dz * rstd * gg.z + bb.z);
    o4[3] = (bf16)(dw * rstd * gg.w + bb.w);
    *(bf16x4*)(out + (size_t)row * DIM + t * 4) = o4;
}

// ------------------------------------------------- weight transpose+convert
// W f32 [K][N]  ->  Wt bf16 [rowoff + n][K]   (32x32 tiles via LDS)
__global__ __launch_bounds__(256) void wtrans_kernel(
    const float* __restrict__ W, bf16* __restrict__ Wt,
    int N, int K, int rowoff)
{
    __shared__ float tile[32][33];
    const int bn = blockIdx.x * 32, bk = blockIdx.y * 32;
    const int r = threadIdx.x >> 3, c4 = (threadIdx.x & 7) * 4;
    const float4 v = *(const float4*)(W + (size_t)(bk + r) * N + bn + c4);
    tile[r][c4 + 0] = v.x; tile[r][c4 + 1] = v.y;
    tile[r][c4 + 2] = v.z; tile[r][c4 + 3] = v.w;
    __syncthreads();
    bf16x4 o;
    #pragma unroll
    for (int j = 0; j < 4; ++j) o[j] = (bf16)tile[c4 + j][r];
    *(bf16x4*)(Wt + (size_t)(rowoff + bn + r) * K + bk + c4) = o;
}

// ---------------------------------------------------------------- GEMM
// C[M,N] = A[M,K](bf16) @ Bt(bf16 [N][K]).  BM=128, BK=32, LDS double-buffer.
// 1-D grid (bn-fast) with XCD-chunked remap (grid %8 == 0 always).
// EPI 0: bf16 store. 1: +bias, GELU, bf16. 2: +bias +resid(f32), f32.
template<int BN, int EPI>
__global__ __launch_bounds__(256) void gemm_kernel(
    const bf16* __restrict__ A, const bf16* __restrict__ Bt,
    const float* __restrict__ bias, const float* __restrict__ resid,
    void* __restrict__ outv, int M, int N, int K)
{
    constexpr int MR  = (BN == 128) ? 4 : 2;
    constexpr int ASZ = 128 * 32, BSZ = BN * 32;
    __shared__ bf16 As[2][ASZ];
    __shared__ bf16 Bs[2][BSZ];

    const int t    = threadIdx.x;
    const int lane = t & 63;
    const int w    = t >> 6;
    const int wm   = (BN == 128) ? (w >> 1) * 64 : w * 32;
    const int wn   = (BN == 128) ? (w & 1) * 64 : 0;
    const int kg   = lane >> 4, lr = lane & 15;

    // XCD-chunked block remap: consecutive chunk per XCD shares A-panels
    const int nwg = gridDim.x;
    const int bid = (blockIdx.x & 7) * (nwg >> 3) + (blockIdx.x >> 3);
    const int nbn = N / BN;
    const int bm  = (bid / nbn) * 128;
    const int bn  = (bid % nbn) * BN;

    f32x4 acc[MR][4] = {};

    auto stage = [&](int buf, int k0) {
        #pragma unroll
        for (int c = 0; c < 2; ++c) {
            const int ci = c * 256 + t;
            gload_lds16(A + (size_t)(bm + (ci >> 2)) * K + k0 + (ci & 3) * 8,
                        &As[buf][ci * 8]);
        }
        #pragma unroll
        for (int c = 0; c < BN / 64; ++c) {
            const int ci = c * 256 + t;
            gload_lds16(Bt + (size_t)(bn + (ci >> 2)) * K + k0 + (ci & 3) * 8,
                        &Bs[buf][ci * 8]);
        }
    };

    stage(0, 0);
    __syncthreads();

    int cur = 0;
    for (int k0 = 0; k0 < K; k0 += 32) {
        if (k0 + 32 < K) stage(cur ^ 1, k0 + 32);   // async prefetch next tile

        bf16x8 af[MR], bfr[4];
        #pragma unroll
        for (int m = 0; m < MR; ++m)
            af[m] = *(const bf16x8*)(&As[cur][(wm + m * 16 + lr) * 32 + kg * 8]);
        #pragma unroll
        for (int n = 0; n < 4; ++n)
            bfr[n] = *(const bf16x8*)(&Bs[cur][(wn + n * 16 + lr) * 32 + kg * 8]);
        #pragma unroll
        for (int m = 0; m < MR; ++m)
            #pragma unroll
            for (int n = 0; n < 4; ++n)
                acc[m][n] = __builtin_amdgcn_mfma_f32_16x16x32_bf16(af[m], bfr[n], acc[m][n], 0, 0, 0);

        __syncthreads();   // waits compute done + prefetch landed
        cur ^= 1;
    }

    // epilogue: D row = wm+m*16+kg*4+j, col = wn+n*16+lr
    #pragma unroll
    for (int m = 0; m < MR; ++m) {
        const int row = bm + wm + m * 16 + kg * 4;
        #pragma unroll
        for (int n = 0; n < 4; ++n) {
            const int col = bn + wn + n * 16 + lr;
            #pragma unroll
            for (int j = 0; j < 4; ++j) {
                const float vv = acc[m][n][j];
                const size_t idx = (size_t)(row + j) * N + col;
                if (EPI == 0) {
                    ((bf16*)outv)[idx] = (bf16)vv;
                } else if (EPI == 1) {
                    const float z = vv + bias[col];
                    const float gl = 0.5f * z * (1.0f + erff(z * 0.70710678118654752f));
                    ((bf16*)outv)[idx] = (bf16)gl;
                } else {
                    ((float*)outv)[idx] = vv + bias[col] + resid[idx];
                }
            }
        }
    }
}

// ------------------------------------------------- MFMA flash attention
// qkv bf16 [TOK][3072] (q|k|v); block = (b,h, 64 q rows), 4 waves x 16 rows.
__global__ __launch_bounds__(256) void attn_kernel(
    const bf16* __restrict__ qkv, bf16* __restrict__ od)
{
    __shared__ bf16 Ks[64][72];
    __shared__ bf16 Vt[64][72];   // [d][k]
    __shared__ bf16 Ps[64][72];   // wave-private rows

    const int bh = blockIdx.y;
    const int b  = bh >> 4, h = bh & 15;
    const int q0 = blockIdx.x * 64;
    const int t  = threadIdx.x, w = t >> 6, lane = t & 63;
    const int kg = lane >> 4, lr = lane & 15;

    const bf16* qbase = qkv + (size_t)b * SEQ * QKVN + h * 64;
    const bf16* kbase = qbase + DIM;
    const bf16* vbase = qbase + 2 * DIM;

    bf16x8 qf0, qf1;
    {
        const bf16* qr = qbase + (size_t)(q0 + w * 16 + lr) * QKVN;
        qf0 = *(const bf16x8*)(qr + kg * 8);
        qf1 = *(const bf16x8*)(qr + 32 + kg * 8);
    }

    f32x4 o_acc[4] = {};
    float m_run[4] = {-1e30f, -1e30f, -1e30f, -1e30f};
    float l_run[4] = {};

    const int rK = t >> 3, oK = (t & 7) * 8;
    const int rp = t >> 3, d0 = (t & 7) * 8;

    for (int kb = 0; kb < SEQ; kb += 64) {
        __syncthreads();
        *(bf16x8*)&Ks[rK][oK] =
            *(const bf16x8*)(kbase + (size_t)(kb + rK) * QKVN + oK);
        *(bf16x8*)&Ks[32 + rK][oK] =
            *(const bf16x8*)(kbase + (size_t)(kb + 32 + rK) * QKVN + oK);
        {
            const bf16x8 v0 = *(const bf16x8*)(vbase + (size_t)(kb + 2 * rp) * QKVN + d0);
            const bf16x8 v1 = *(const bf16x8*)(vbase + (size_t)(kb + 2 * rp + 1) * QKVN + d0);
            #pragma unroll
            for (int j = 0; j < 8; ++j) {
                bf16x2 p; p[0] = v0[j]; p[1] = v1[j];
                *(bf16x2*)&Vt[d0 + j][2 * rp] = p;
            }
        }
        __syncthreads();

        f32x4 s[4] = {};
        #pragma unroll
        for (int n = 0; n < 4; ++n) {
            const bf16x8 kf0 = *(const bf16x8*)&Ks[n * 16 + lr][kg * 8];
            const bf16x8 kf1 = *(const bf16x8*)&Ks[n * 16 + lr][32 + kg * 8];
            s[n] = __builtin_amdgcn_mfma_f32_16x16x32_bf16(qf0, kf0, s[n], 0, 0, 0);
            s[n] = __builtin_amdgcn_mfma_f32_16x16x32_bf16(qf1, kf1, s[n], 0, 0, 0);
        }
        #pragma unroll
        for (int n = 0; n < 4; ++n) s[n] *= 0.125f;

        float corr[4], rs[4];
        #pragma unroll
        for (int j = 0; j < 4; ++j) {
            float mx = fmaxf(fmaxf(s[0][j], s[1][j]), fmaxf(s[2][j], s[3][j]));
            #pragma unroll
            for (int o = 1; o < 16; o <<= 1) mx = fmaxf(mx, __shfl_xor(mx, o, 64));
            const float mn = fmaxf(m_run[j], mx);
            corr[j] = __expf(m_run[j] - mn);
            m_run[j] = mn;
            rs[j] = 0.f;
        }
        #pragma unroll
        for (int n = 0; n < 4; ++n)
            #pragma unroll
            for (int j = 0; j < 4; ++j) {
                const float e = __expf(s[n][j] - m_run[j]);
                s[n][j] = e; rs[j] += e;
            }
        #pragma unroll
        for (int j = 0; j < 4; ++j) {
            #pragma unroll
            for (int o = 1; o < 16; o <<= 1) rs[j] += __shfl_xor(rs[j], o, 64);
            l_run[j] = l_run[j] * corr[j] + rs[j];
        }
        #pragma unroll
        for (int nd = 0; nd < 4; ++nd)
            #pragma unroll
            for (int j = 0; j < 4; ++j) o_acc[nd][j] *= corr[j];

        #pragma unroll
        for (int n = 0; n < 4; ++n)
            #pragma unroll
            for (int j = 0; j < 4; ++j)
                Ps[w * 16 + kg * 4 + j][n * 16 + lr] = (bf16)s[n][j];

        const bf16x8 pf0 = *(const bf16x8*)&Ps[w * 16 + lr][kg * 8];
        const bf16x8 pf1 = *(const bf16x8*)&Ps[w * 16 + lr][32 + kg * 8];
        #pragma unroll
        for (int nd = 0; nd < 4; ++nd) {
            const bf16x8 vf0 = *(const bf16x8*)&Vt[nd * 16 + lr][kg * 8];
            const bf16x8 vf1 = *(const bf16x8*)&Vt[nd * 16 + lr][32 + kg * 8];
            o_acc[nd] = __builtin_amdgcn_mfma_f32_16x16x32_bf16(pf0, vf0, o_acc[nd], 0, 0, 0);
            o_acc[nd] = __builtin_amdgcn_mfma_f32_16x16x32_bf16(pf1, vf1, o_acc[nd], 0, 0, 0);
        }
    }

    float inv[4];
    #pragma unroll
    for (int j = 0; j < 4; ++j) inv[j] = 1.0f / l_run[j];
    bf16* ob = od + (size_t)(b * SEQ + q0 + w * 16 + kg * 4) * DIM + h * 64;
    #pragma unroll
    for (int nd = 0; nd < 4; ++nd)
        #pragma unroll
        for (int j = 0; j < 4; ++j)
            ob[(size_t)j * DIM + nd * 16 + lr] = (bf16)(o_acc[nd][j] * inv[j]);
}

// ---------------------------------------------------------------- launch
extern "C" void kernel_launch(void* const* d_in, const int* in_sizes, int n_in,
                              void* d_out, int out_size, void* d_ws, size_t ws_size,
                              hipStream_t stream)
{
    const float* x    = (const float*)d_in[0];
    const float* ln1w = (const float*)d_in[1];
    const float* ln1b = (const float*)d_in[2];
    const float* Wq   = (const float*)d_in[3];
    const float* Wk   = (const float*)d_in[4];
    const float* Wv   = (const float*)d_in[5];
    const float* Wo   = (const float*)d_in[6];
    const float* bo   = (const float*)d_in[7];
    const float* ln2w = (const float*)d_in[8];
    const float* ln2b = (const float*)d_in[9];
    const float* W1   = (const float*)d_in[10];
    const float* b1   = (const float*)d_in[11];
    const float* W2   = (const float*)d_in[12];
    const float* b2   = (const float*)d_in[13];

    char* ws = (char*)d_ws;
    float* xbuf  = (float*)(ws);                 // 8 MB
    bf16*  hbuf  = (bf16*)(ws + (8ull  << 20));  // 4 MB
    bf16*  qkvb  = (bf16*)(ws + (12ull << 20));  // 12 MB
    bf16*  obuf  = (bf16*)(ws + (24ull << 20));  // 4 MB
    bf16*  gbuf  = (bf16*)(ws + (28ull << 20));  // 16 MB
    bf16*  wqkvt = (bf16*)(ws + (44ull << 20));  // 6 MB  [3072][1024]
    bf16*  wot   = (bf16*)(ws + (50ull << 20));  // 2 MB  [1024][1024]
    bf16*  w1t   = (bf16*)(ws + (52ull << 20));  // 8 MB  [4096][1024]
    bf16*  w2t   = (bf16*)(ws + (60ull << 20));  // 8 MB  [1024][4096]

    hipMemcpyAsync(xbuf, x, (size_t)TOK * DIM * sizeof(float),
                   hipMemcpyDeviceToDevice, stream);

    const size_t DD = (size_t)DIM * DIM, DF = (size_t)DIM * FF;
    for (int l = 0; l < LAYERS; ++l) {
        wtrans_kernel<<<dim3(32, 32), 256, 0, stream>>>(Wq + l * DD, wqkvt, DIM, DIM, 0);
        wtrans_kernel<<<dim3(32, 32), 256, 0, stream>>>(Wk + l * DD, wqkvt, DIM, DIM, DIM);
        wtrans_kernel<<<dim3(32, 32), 256, 0, stream>>>(Wv + l * DD, wqkvt, DIM, DIM, 2 * DIM);
        wtrans_kernel<<<dim3(32, 32), 256, 0, stream>>>(Wo + l * DD, wot, DIM, DIM, 0);
        wtrans_kernel<<<dim3(128, 32), 256, 0, stream>>>(W1 + l * DF, w1t, FF, DIM, 0);
        wtrans_kernel<<<dim3(32, 128), 256, 0, stream>>>(W2 + l * DF, w2t, DIM, FF, 0);

        ln_kernel<<<TOK, 256, 0, stream>>>(xbuf, ln1w + l * DIM, ln1b + l * DIM, hbuf);

        gemm_kernel<128, 0><<<16 * 24, 256, 0, stream>>>(
            hbuf, wqkvt, nullptr, nullptr, qkvb, TOK, QKVN, DIM);

        attn_kernel<<<dim3(SEQ / 64, BATCH * HEADS), 256, 0, stream>>>(qkvb, obuf);

        gemm_kernel<64, 2><<<16 * 16, 256, 0, stream>>>(
            obuf, wot, bo + l * DIM, xbuf, xbuf, TOK, DIM, DIM);

        ln_kernel<<<TOK, 256, 0, stream>>>(xbuf, ln2w + l * DIM, ln2b + l * DIM, hbuf);

        gemm_kernel<128, 1><<<16 * 32, 256, 0, stream>>>(
            hbuf, w1t, b1 + l * FF, nullptr, gbuf, TOK, FF, DIM);

        gemm_kernel<64, 2><<<16 * 16, 256, 0, stream>>>(
            gbuf, w2t, b2 + l * DIM, xbuf, xbuf, TOK, DIM, FF);
    }

    hipMemcpyAsync(d_out, xbuf, (size_t)TOK * DIM * sizeof(float),
                   hipMemcpyDeviceToDevice, stream);
}

// Round 4
// 745.530 us; speedup vs baseline: 3.1968x; 1.1809x over previous
//
#include <hip/hip_runtime.h>
#include <hip/hip_bf16.h>

using bf16   = __bf16;
using bf16x2 = __attribute__((ext_vector_type(2))) __bf16;
using bf16x4 = __attribute__((ext_vector_type(4))) __bf16;
using bf16x8 = __attribute__((ext_vector_type(8))) __bf16;
using f32x4  = __attribute__((ext_vector_type(4))) float;

constexpr int LAYERS = 4;
constexpr int BATCH  = 2;
constexpr int SEQ    = 1024;
constexpr int DIM    = 1024;
constexpr int FF     = 4096;
constexpr int HEADS  = 16;
constexpr int TOK    = BATCH * SEQ;   // 2048
constexpr int QKVN   = 3 * DIM;       // 3072
constexpr float EPS  = 1e-5f;

// async global->LDS, 16B per lane (HW: wave-uniform LDS base + lane*16)
__device__ __forceinline__ void gload_lds16(const void* g, void* l) {
    __builtin_amdgcn_global_load_lds(
        (const __attribute__((address_space(1))) void*)g,
        (__attribute__((address_space(3))) void*)l, 16, 0, 0);
}

// ---------------------------------------------------------------- LayerNorm
__global__ __launch_bounds__(256) void ln_kernel(
    const float* __restrict__ x, const float* __restrict__ g,
    const float* __restrict__ bt, bf16* __restrict__ out)
{
    __shared__ float red[8];
    const int row = blockIdx.x, t = threadIdx.x;
    const float4 v = ((const float4*)(x + (size_t)row * DIM))[t];

    float s = v.x + v.y + v.z + v.w;
    #pragma unroll
    for (int o = 32; o; o >>= 1) s += __shfl_down(s, o, 64);
    if ((t & 63) == 0) red[t >> 6] = s;
    __syncthreads();
    const float mean = (red[0] + red[1] + red[2] + red[3]) * (1.0f / DIM);

    const float dx = v.x - mean, dy = v.y - mean, dz = v.z - mean, dw = v.w - mean;
    float q = dx * dx + dy * dy + dz * dz + dw * dw;
    #pragma unroll
    for (int o = 32; o; o >>= 1) q += __shfl_down(q, o, 64);
    if ((t & 63) == 0) red[4 + (t >> 6)] = q;
    __syncthreads();
    const float var = (red[4] + red[5] + red[6] + red[7]) * (1.0f / DIM);
    const float rstd = rsqrtf(var + EPS);

    const float4 gg = ((const float4*)g)[t];
    const float4 bb = ((const float4*)bt)[t];
    bf16x4 o4;
    o4[0] = (bf16)(dx * rstd * gg.x + bb.x);
    o4[1] = (bf16)(dy * rstd * gg.y + bb.y);
    o4[2] = (bf16)(dz * rstd * gg.z + bb.z);
    o4[3] = (bf16)(dw * rstd * gg.w + bb.w);
    *(bf16x4*)(out + (size_t)row * DIM + t * 4) = o4;
}

// ------------------------------------- split-K combine (+bias) fused w/ LN
// x += p0 + p1 + bias;  optionally out = LN(x, g, bt)
template<bool DO_LN>
__global__ __launch_bounds__(256) void lncomb_kernel(
    float* __restrict__ x, const float* __restrict__ p,
    const float* __restrict__ bias, const float* __restrict__ g,
    const float* __restrict__ bt, bf16* __restrict__ out)
{
    __shared__ float red[8];
    const int row = blockIdx.x, t = threadIdx.x;
    float4 v = ((const float4*)(x + (size_t)row * DIM))[t];
    const float4 a0 = ((const float4*)(p + (size_t)row * DIM))[t];
    const float4 a1 = ((const float4*)(p + (size_t)(TOK + row) * DIM))[t];
    const float4 bv = ((const float4*)bias)[t];
    v.x += a0.x + a1.x + bv.x;
    v.y += a0.y + a1.y + bv.y;
    v.z += a0.z + a1.z + bv.z;
    v.w += a0.w + a1.w + bv.w;
    ((float4*)(x + (size_t)row * DIM))[t] = v;
    if (!DO_LN) return;

    float s = v.x + v.y + v.z + v.w;
    #pragma unroll
    for (int o = 32; o; o >>= 1) s += __shfl_down(s, o, 64);
    if ((t & 63) == 0) red[t >> 6] = s;
    __syncthreads();
    const float mean = (red[0] + red[1] + red[2] + red[3]) * (1.0f / DIM);

    const float dx = v.x - mean, dy = v.y - mean, dz = v.z - mean, dw = v.w - mean;
    float q = dx * dx + dy * dy + dz * dz + dw * dw;
    #pragma unroll
    for (int o = 32; o; o >>= 1) q += __shfl_down(q, o, 64);
    if ((t & 63) == 0) red[4 + (t >> 6)] = q;
    __syncthreads();
    const float var = (red[4] + red[5] + red[6] + red[7]) * (1.0f / DIM);
    const float rstd = rsqrtf(var + EPS);

    const float4 gg = ((const float4*)g)[t];
    const float4 bb = ((const float4*)bt)[t];
    bf16x4 o4;
    o4[0] = (bf16)(dx * rstd * gg.x + bb.x);
    o4[1] = (bf16)(dy * rstd * gg.y + bb.y);
    o4[2] = (bf16)(dz * rstd * gg.z + bb.z);
    o4[3] = (bf16)(dw * rstd * gg.w + bb.w);
    *(bf16x4*)(out + (size_t)row * DIM + t * 4) = o4;
}

// ------------------------------------------------- weight transpose+convert
__global__ __launch_bounds__(256) void wtrans_kernel(
    const float* __restrict__ W, bf16* __restrict__ Wt,
    int N, int K, int rowoff)
{
    __shared__ float tile[32][33];
    const int bn = blockIdx.x * 32, bk = blockIdx.y * 32;
    const int r = threadIdx.x >> 3, c4 = (threadIdx.x & 7) * 4;
    const float4 v = *(const float4*)(W + (size_t)(bk + r) * N + bn + c4);
    tile[r][c4 + 0] = v.x; tile[r][c4 + 1] = v.y;
    tile[r][c4 + 2] = v.z; tile[r][c4 + 3] = v.w;
    __syncthreads();
    bf16x4 o;
    #pragma unroll
    for (int j = 0; j < 4; ++j) o[j] = (bf16)tile[c4 + j][r];
    *(bf16x4*)(Wt + (size_t)(rowoff + bn + r) * K + bk + c4) = o;
}

// ---------------------------------------------------------------- GEMM
// C = A[M,Kfull](bf16) @ Bt(bf16 [N][Kfull]).  BM=128, BK=32, dbuf LDS.
// SK-way split-K: block computes slice ks over Kfull/SK columns.
// EPI 0: bf16 store. 1: +bias GELU bf16. 3: f32 partial at outv[ks*M*N].
template<int BN, int EPI, int SK>
__global__ __launch_bounds__(256) void gemm_kernel(
    const bf16* __restrict__ A, const bf16* __restrict__ Bt,
    const float* __restrict__ bias, void* __restrict__ outv,
    int M, int N, int Kfull)
{
    constexpr int MR  = (BN == 128) ? 4 : 2;
    constexpr int ASZ = 128 * 32, BSZ = BN * 32;
    __shared__ bf16 As[2][ASZ];
    __shared__ bf16 Bs[2][BSZ];

    const int t    = threadIdx.x;
    const int lane = t & 63;
    const int w    = t >> 6;
    const int wm   = (BN == 128) ? (w >> 1) * 64 : w * 32;
    const int wn   = (BN == 128) ? (w & 1) * 64 : 0;
    const int kg   = lane >> 4, lr = lane & 15;

    // XCD-chunked remap (grid %8 == 0): contiguous bid range per XCD
    const int nwg = gridDim.x;
    const int bid = (blockIdx.x & 7) * (nwg >> 3) + (blockIdx.x >> 3);
    const int nbn = N / BN, nbm = M / 128;
    const int ks  = (SK > 1) ? bid / (nbm * nbn) : 0;
    const int r   = (SK > 1) ? bid % (nbm * nbn) : bid;
    // SK==1: bm-fast (per-XCD chunk shares few B-panels, reuses A via L2)
    // SK>1 : bn-fast (square-ish chunk)
    const int bm  = ((SK > 1) ? (r / nbn) : (r % nbm)) * 128;
    const int bn  = ((SK > 1) ? (r % nbn) : (r / nbm)) * BN;

    const int Ksl = Kfull / SK;
    const int kof = ks * Ksl;

    f32x4 acc[MR][4] = {};

    auto stage = [&](int buf, int k0) {
        #pragma unroll
        for (int c = 0; c < 2; ++c) {
            const int ci = c * 256 + t;
            gload_lds16(A + (size_t)(bm + (ci >> 2)) * Kfull + kof + k0 + (ci & 3) * 8,
                        &As[buf][ci * 8]);
        }
        #pragma unroll
        for (int c = 0; c < BN / 64; ++c) {
            const int ci = c * 256 + t;
            gload_lds16(Bt + (size_t)(bn + (ci >> 2)) * Kfull + kof + k0 + (ci & 3) * 8,
                        &Bs[buf][ci * 8]);
        }
    };

    stage(0, 0);
    __syncthreads();

    int cur = 0;
    for (int k0 = 0; k0 < Ksl; k0 += 32) {
        if (k0 + 32 < Ksl) stage(cur ^ 1, k0 + 32);

        bf16x8 af[MR], bfr[4];
        #pragma unroll
        for (int m = 0; m < MR; ++m)
            af[m] = *(const bf16x8*)(&As[cur][(wm + m * 16 + lr) * 32 + kg * 8]);
        #pragma unroll
        for (int n = 0; n < 4; ++n)
            bfr[n] = *(const bf16x8*)(&Bs[cur][(wn + n * 16 + lr) * 32 + kg * 8]);
        #pragma unroll
        for (int m = 0; m < MR; ++m)
            #pragma unroll
            for (int n = 0; n < 4; ++n)
                acc[m][n] = __builtin_amdgcn_mfma_f32_16x16x32_bf16(af[m], bfr[n], acc[m][n], 0, 0, 0);

        __syncthreads();
        cur ^= 1;
    }

    // epilogue: D row = wm+m*16+kg*4+j, col = wn+n*16+lr
    #pragma unroll
    for (int m = 0; m < MR; ++m) {
        const int row = bm + wm + m * 16 + kg * 4;
        #pragma unroll
        for (int n = 0; n < 4; ++n) {
            const int col = bn + wn + n * 16 + lr;
            #pragma unroll
            for (int j = 0; j < 4; ++j) {
                const float vv = acc[m][n][j];
                const size_t idx = (size_t)(row + j) * N + col;
                if (EPI == 0) {
                    ((bf16*)outv)[idx] = (bf16)vv;
                } else if (EPI == 1) {
                    const float z = vv + bias[col];
                    const float gl = 0.5f * z * (1.0f + erff(z * 0.70710678118654752f));
                    ((bf16*)outv)[idx] = (bf16)gl;
                } else {
                    ((float*)outv)[(size_t)ks * M * N + idx] = vv;
                }
            }
        }
    }
}

// ------------------------------------------------- MFMA flash attention
__global__ __launch_bounds__(256) void attn_kernel(
    const bf16* __restrict__ qkv, bf16* __restrict__ od)
{
    __shared__ bf16 Ks[64][72];
    __shared__ bf16 Vt[64][72];   // [d][k]
    __shared__ bf16 Ps[64][72];   // wave-private rows

    const int bh = blockIdx.y;
    const int b  = bh >> 4, h = bh & 15;
    const int q0 = blockIdx.x * 64;
    const int t  = threadIdx.x, w = t >> 6, lane = t & 63;
    const int kg = lane >> 4, lr = lane & 15;

    const bf16* qbase = qkv + (size_t)b * SEQ * QKVN + h * 64;
    const bf16* kbase = qbase + DIM;
    const bf16* vbase = qbase + 2 * DIM;

    bf16x8 qf0, qf1;
    {
        const bf16* qr = qbase + (size_t)(q0 + w * 16 + lr) * QKVN;
        qf0 = *(const bf16x8*)(qr + kg * 8);
        qf1 = *(const bf16x8*)(qr + 32 + kg * 8);
    }

    f32x4 o_acc[4] = {};
    float m_run[4] = {-1e30f, -1e30f, -1e30f, -1e30f};
    float l_run[4] = {};

    const int rK = t >> 3, oK = (t & 7) * 8;
    const int rp = t >> 3, d0 = (t & 7) * 8;

    for (int kb = 0; kb < SEQ; kb += 64) {
        __syncthreads();
        *(bf16x8*)&Ks[rK][oK] =
            *(const bf16x8*)(kbase + (size_t)(kb + rK) * QKVN + oK);
        *(bf16x8*)&Ks[32 + rK][oK] =
            *(const bf16x8*)(kbase + (size_t)(kb + 32 + rK) * QKVN + oK);
        {
            const bf16x8 v0 = *(const bf16x8*)(vbase + (size_t)(kb + 2 * rp) * QKVN + d0);
            const bf16x8 v1 = *(const bf16x8*)(vbase + (size_t)(kb + 2 * rp + 1) * QKVN + d0);
            #pragma unroll
            for (int j = 0; j < 8; ++j) {
                bf16x2 p; p[0] = v0[j]; p[1] = v1[j];
                *(bf16x2*)&Vt[d0 + j][2 * rp] = p;
            }
        }
        __syncthreads();

        f32x4 s[4] = {};
        #pragma unroll
        for (int n = 0; n < 4; ++n) {
            const bf16x8 kf0 = *(const bf16x8*)&Ks[n * 16 + lr][kg * 8];
            const bf16x8 kf1 = *(const bf16x8*)&Ks[n * 16 + lr][32 + kg * 8];
            s[n] = __builtin_amdgcn_mfma_f32_16x16x32_bf16(qf0, kf0, s[n], 0, 0, 0);
            s[n] = __builtin_amdgcn_mfma_f32_16x16x32_bf16(qf1, kf1, s[n], 0, 0, 0);
        }
        #pragma unroll
        for (int n = 0; n < 4; ++n) s[n] *= 0.125f;

        float corr[4], rs[4];
        #pragma unroll
        for (int j = 0; j < 4; ++j) {
            float mx = fmaxf(fmaxf(s[0][j], s[1][j]), fmaxf(s[2][j], s[3][j]));
            #pragma unroll
            for (int o = 1; o < 16; o <<= 1) mx = fmaxf(mx, __shfl_xor(mx, o, 64));
            const float mn = fmaxf(m_run[j], mx);
            corr[j] = __expf(m_run[j] - mn);
            m_run[j] = mn;
            rs[j] = 0.f;
        }
        #pragma unroll
        for (int n = 0; n < 4; ++n)
            #pragma unroll
            for (int j = 0; j < 4; ++j) {
                const float e = __expf(s[n][j] - m_run[j]);
                s[n][j] = e; rs[j] += e;
            }
        #pragma unroll
        for (int j = 0; j < 4; ++j) {
            #pragma unroll
            for (int o = 1; o < 16; o <<= 1) rs[j] += __shfl_xor(rs[j], o, 64);
            l_run[j] = l_run[j] * corr[j] + rs[j];
        }
        #pragma unroll
        for (int nd = 0; nd < 4; ++nd)
            #pragma unroll
            for (int j = 0; j < 4; ++j) o_acc[nd][j] *= corr[j];

        #pragma unroll
        for (int n = 0; n < 4; ++n)
            #pragma unroll
            for (int j = 0; j < 4; ++j)
                Ps[w * 16 + kg * 4 + j][n * 16 + lr] = (bf16)s[n][j];

        const bf16x8 pf0 = *(const bf16x8*)&Ps[w * 16 + lr][kg * 8];
        const bf16x8 pf1 = *(const bf16x8*)&Ps[w * 16 + lr][32 + kg * 8];
        #pragma unroll
        for (int nd = 0; nd < 4; ++nd) {
            const bf16x8 vf0 = *(const bf16x8*)&Vt[nd * 16 + lr][kg * 8];
            const bf16x8 vf1 = *(const bf16x8*)&Vt[nd * 16 + lr][32 + kg * 8];
            o_acc[nd] = __builtin_amdgcn_mfma_f32_16x16x32_bf16(pf0, vf0, o_acc[nd], 0, 0, 0);
            o_acc[nd] = __builtin_amdgcn_mfma_f32_16x16x32_bf16(pf1, vf1, o_acc[nd], 0, 0, 0);
        }
    }

    float inv[4];
    #pragma unroll
    for (int j = 0; j < 4; ++j) inv[j] = 1.0f / l_run[j];
    bf16* ob = od + (size_t)(b * SEQ + q0 + w * 16 + kg * 4) * DIM + h * 64;
    #pragma unroll
    for (int nd = 0; nd < 4; ++nd)
        #pragma unroll
        for (int j = 0; j < 4; ++j)
            ob[(size_t)j * DIM + nd * 16 + lr] = (bf16)(o_acc[nd][j] * inv[j]);
}

// ---------------------------------------------------------------- launch
extern "C" void kernel_launch(void* const* d_in, const int* in_sizes, int n_in,
                              void* d_out, int out_size, void* d_ws, size_t ws_size,
                              hipStream_t stream)
{
    const float* x    = (const float*)d_in[0];
    const float* ln1w = (const float*)d_in[1];
    const float* ln1b = (const float*)d_in[2];
    const float* Wq   = (const float*)d_in[3];
    const float* Wk   = (const float*)d_in[4];
    const float* Wv   = (const float*)d_in[5];
    const float* Wo   = (const float*)d_in[6];
    const float* bo   = (const float*)d_in[7];
    const float* ln2w = (const float*)d_in[8];
    const float* ln2b = (const float*)d_in[9];
    const float* W1   = (const float*)d_in[10];
    const float* b1   = (const float*)d_in[11];
    const float* W2   = (const float*)d_in[12];
    const float* b2   = (const float*)d_in[13];

    char* ws = (char*)d_ws;
    float* xbuf  = (float*)(ws);                 // 8 MB f32 residual
    bf16*  hbuf  = (bf16*)(ws + (8ull  << 20));  // 4 MB
    bf16*  qkvb  = (bf16*)(ws + (12ull << 20));  // 12 MB
    bf16*  obuf  = (bf16*)(ws + (24ull << 20));  // 4 MB
    bf16*  gbuf  = (bf16*)(ws + (28ull << 20));  // 16 MB
    bf16*  wqkvt = (bf16*)(ws + (44ull << 20));  // 6 MB  [3072][1024]
    bf16*  wot   = (bf16*)(ws + (50ull << 20));  // 2 MB  [1024][1024]
    bf16*  w1t   = (bf16*)(ws + (52ull << 20));  // 8 MB  [4096][1024]
    bf16*  w2t   = (bf16*)(ws + (60ull << 20));  // 8 MB  [1024][4096]
    float* pbuf  = (float*)(ws + (68ull << 20)); // 16 MB [2][TOK][DIM] f32

    hipMemcpyAsync(xbuf, x, (size_t)TOK * DIM * sizeof(float),
                   hipMemcpyDeviceToDevice, stream);

    const size_t DD = (size_t)DIM * DIM, DF = (size_t)DIM * FF;
    for (int l = 0; l < LAYERS; ++l) {
        wtrans_kernel<<<dim3(32, 32), 256, 0, stream>>>(Wq + l * DD, wqkvt, DIM, DIM, 0);
        wtrans_kernel<<<dim3(32, 32), 256, 0, stream>>>(Wk + l * DD, wqkvt, DIM, DIM, DIM);
        wtrans_kernel<<<dim3(32, 32), 256, 0, stream>>>(Wv + l * DD, wqkvt, DIM, DIM, 2 * DIM);
        wtrans_kernel<<<dim3(32, 32), 256, 0, stream>>>(Wo + l * DD, wot, DIM, DIM, 0);
        wtrans_kernel<<<dim3(128, 32), 256, 0, stream>>>(W1 + l * DF, w1t, FF, DIM, 0);
        wtrans_kernel<<<dim3(32, 128), 256, 0, stream>>>(W2 + l * DF, w2t, DIM, FF, 0);

        if (l == 0)
            ln_kernel<<<TOK, 256, 0, stream>>>(xbuf, ln1w, ln1b, hbuf);
        // (l>0: hbuf already holds LN1 output from previous layer's lncomb)

        gemm_kernel<64, 0, 1><<<16 * 48, 256, 0, stream>>>(
            hbuf, wqkvt, nullptr, qkvb, TOK, QKVN, DIM);

        attn_kernel<<<dim3(SEQ / 64, BATCH * HEADS), 256, 0, stream>>>(qkvb, obuf);

        gemm_kernel<64, 3, 2><<<16 * 8 * 2 * 2, 256, 0, stream>>>(
            obuf, wot, nullptr, pbuf, TOK, DIM, DIM);

        lncomb_kernel<true><<<TOK, 256, 0, stream>>>(
            xbuf, pbuf, bo + l * DIM, ln2w + l * DIM, ln2b + l * DIM, hbuf);

        gemm_kernel<128, 1, 1><<<16 * 32, 256, 0, stream>>>(
            hbuf, w1t, b1 + l * FF, gbuf, TOK, FF, DIM);

        gemm_kernel<64, 3, 2><<<16 * 8 * 2 * 2, 256, 0, stream>>>(
            gbuf, w2t, nullptr, pbuf, TOK, DIM, FF);

        if (l + 1 < LAYERS)
            lncomb_kernel<true><<<TOK, 256, 0, stream>>>(
                xbuf, pbuf, b2 + l * DIM, ln1w + (l + 1) * DIM, ln1b + (l + 1) * DIM, hbuf);
        else
            lncomb_kernel<false><<<TOK, 256, 0, stream>>>(
                xbuf, pbuf, b2 + l * DIM, nullptr, nullptr, nullptr);
    }

    hipMemcpyAsync(d_out, xbuf, (size_t)TOK * DIM * sizeof(float),
                   hipMemcpyDeviceToDevice, stream);
}

// Round 5
// 708.452 us; speedup vs baseline: 3.3641x; 1.0523x over previous
//
#include <hip/hip_runtime.h>
#include <hip/hip_bf16.h>

using bf16   = __bf16;
using bf16x2 = __attribute__((ext_vector_type(2))) __bf16;
using bf16x4 = __attribute__((ext_vector_type(4))) __bf16;
using bf16x8 = __attribute__((ext_vector_type(8))) __bf16;
using f32x4  = __attribute__((ext_vector_type(4))) float;

constexpr int LAYERS = 4;
constexpr int BATCH  = 2;
constexpr int SEQ    = 1024;
constexpr int DIM    = 1024;
constexpr int FF     = 4096;
constexpr int HEADS  = 16;
constexpr int TOK    = BATCH * SEQ;   // 2048
constexpr int QKVN   = 3 * DIM;       // 3072
constexpr float EPS  = 1e-5f;

// async global->LDS, 16B per lane (HW: wave-uniform LDS base + lane*16)
__device__ __forceinline__ void gload_lds16(const void* g, void* l) {
    __builtin_amdgcn_global_load_lds(
        (const __attribute__((address_space(1))) void*)g,
        (__attribute__((address_space(3))) void*)l, 16, 0, 0);
}

// ---------------------------------------------------------------- LayerNorm
__global__ __launch_bounds__(256) void ln_kernel(
    const float* __restrict__ x, const float* __restrict__ g,
    const float* __restrict__ bt, bf16* __restrict__ out)
{
    __shared__ float red[8];
    const int row = blockIdx.x, t = threadIdx.x;
    const float4 v = ((const float4*)(x + (size_t)row * DIM))[t];

    float s = v.x + v.y + v.z + v.w;
    #pragma unroll
    for (int o = 32; o; o >>= 1) s += __shfl_down(s, o, 64);
    if ((t & 63) == 0) red[t >> 6] = s;
    __syncthreads();
    const float mean = (red[0] + red[1] + red[2] + red[3]) * (1.0f / DIM);

    const float dx = v.x - mean, dy = v.y - mean, dz = v.z - mean, dw = v.w - mean;
    float q = dx * dx + dy * dy + dz * dz + dw * dw;
    #pragma unroll
    for (int o = 32; o; o >>= 1) q += __shfl_down(q, o, 64);
    if ((t & 63) == 0) red[4 + (t >> 6)] = q;
    __syncthreads();
    const float var = (red[4] + red[5] + red[6] + red[7]) * (1.0f / DIM);
    const float rstd = rsqrtf(var + EPS);

    const float4 gg = ((const float4*)g)[t];
    const float4 bb = ((const float4*)bt)[t];
    bf16x4 o4;
    o4[0] = (bf16)(dx * rstd * gg.x + bb.x);
    o4[1] = (bf16)(dy * rstd * gg.y + bb.y);
    o4[2] = (bf16)(dz * rstd * gg.z + bb.z);
    o4[3] = (bf16)(dw * rstd * gg.w + bb.w);
    *(bf16x4*)(out + (size_t)row * DIM + t * 4) = o4;
}

// ------------------------------------- split-K combine (+bias) fused w/ LN
// x += p0 + p1 + bias;  optionally out = LN(x, g, bt)
template<bool DO_LN>
__global__ __launch_bounds__(256) void lncomb_kernel(
    float* __restrict__ x, const float* __restrict__ p,
    const float* __restrict__ bias, const float* __restrict__ g,
    const float* __restrict__ bt, bf16* __restrict__ out)
{
    __shared__ float red[8];
    const int row = blockIdx.x, t = threadIdx.x;
    float4 v = ((const float4*)(x + (size_t)row * DIM))[t];
    const float4 a0 = ((const float4*)(p + (size_t)row * DIM))[t];
    const float4 a1 = ((const float4*)(p + (size_t)(TOK + row) * DIM))[t];
    const float4 bv = ((const float4*)bias)[t];
    v.x += a0.x + a1.x + bv.x;
    v.y += a0.y + a1.y + bv.y;
    v.z += a0.z + a1.z + bv.z;
    v.w += a0.w + a1.w + bv.w;
    ((float4*)(x + (size_t)row * DIM))[t] = v;
    if (!DO_LN) return;

    float s = v.x + v.y + v.z + v.w;
    #pragma unroll
    for (int o = 32; o; o >>= 1) s += __shfl_down(s, o, 64);
    if ((t & 63) == 0) red[t >> 6] = s;
    __syncthreads();
    const float mean = (red[0] + red[1] + red[2] + red[3]) * (1.0f / DIM);

    const float dx = v.x - mean, dy = v.y - mean, dz = v.z - mean, dw = v.w - mean;
    float q = dx * dx + dy * dy + dz * dz + dw * dw;
    #pragma unroll
    for (int o = 32; o; o >>= 1) q += __shfl_down(q, o, 64);
    if ((t & 63) == 0) red[4 + (t >> 6)] = q;
    __syncthreads();
    const float var = (red[4] + red[5] + red[6] + red[7]) * (1.0f / DIM);
    const float rstd = rsqrtf(var + EPS);

    const float4 gg = ((const float4*)g)[t];
    const float4 bb = ((const float4*)bt)[t];
    bf16x4 o4;
    o4[0] = (bf16)(dx * rstd * gg.x + bb.x);
    o4[1] = (bf16)(dy * rstd * gg.y + bb.y);
    o4[2] = (bf16)(dz * rstd * gg.z + bb.z);
    o4[3] = (bf16)(dw * rstd * gg.w + bb.w);
    *(bf16x4*)(out + (size_t)row * DIM + t * 4) = o4;
}

// ------------------------------ fused weight transpose+convert (all of one layer)
// 12288 blocks: [0,3072) Wq|Wk|Wv -> wqkvt, [3072,4096) Wo -> wot,
// [4096,8192) W1 -> w1t, [8192,12288) W2 -> w2t.  32x32 tiles.
__global__ __launch_bounds__(256) void wtrans_all_kernel(
    const float* __restrict__ Wq, const float* __restrict__ Wk,
    const float* __restrict__ Wv, const float* __restrict__ Wo,
    const float* __restrict__ W1, const float* __restrict__ W2,
    bf16* __restrict__ wqkvt, bf16* __restrict__ wot,
    bf16* __restrict__ w1t, bf16* __restrict__ w2t)
{
    __shared__ float tile[32][33];
    const int bid = blockIdx.x;
    const float* W; bf16* Wt; int N, K, rowoff, bx, by;
    if (bid < 3072) {
        const int seg = bid >> 10, r = bid & 1023;
        W = (seg == 0) ? Wq : (seg == 1) ? Wk : Wv;
        Wt = wqkvt; N = DIM; K = DIM; rowoff = seg * DIM;
        bx = r & 31; by = r >> 5;
    } else if (bid < 4096) {
        const int r = bid - 3072;
        W = Wo; Wt = wot; N = DIM; K = DIM; rowoff = 0;
        bx = r & 31; by = r >> 5;
    } else if (bid < 8192) {
        const int r = bid - 4096;
        W = W1; Wt = w1t; N = FF; K = DIM; rowoff = 0;
        bx = r & 127; by = r >> 7;
    } else {
        const int r = bid - 8192;
        W = W2; Wt = w2t; N = DIM; K = FF; rowoff = 0;
        bx = r & 31; by = r >> 5;
    }
    const int bn = bx * 32, bk = by * 32;
    const int r = threadIdx.x >> 3, c4 = (threadIdx.x & 7) * 4;
    const float4 v = *(const float4*)(W + (size_t)(bk + r) * N + bn + c4);
    tile[r][c4 + 0] = v.x; tile[r][c4 + 1] = v.y;
    tile[r][c4 + 2] = v.z; tile[r][c4 + 3] = v.w;
    __syncthreads();
    bf16x4 o;
    #pragma unroll
    for (int j = 0; j < 4; ++j) o[j] = (bf16)tile[c4 + j][r];
    *(bf16x4*)(Wt + (size_t)(rowoff + bn + r) * K + bk + c4) = o;
}

// ---------------------------------------------------------------- GEMM
// C = A[M,Kfull](bf16) @ Bt(bf16 [N][Kfull]).  BM=128, BK=32, dbuf LDS.
// SK-way split-K.  EPI 0: bf16. 1: +bias GELU bf16. 3: f32 partial.
template<int BN, int EPI, int SK>
__global__ __launch_bounds__(256) void gemm_kernel(
    const bf16* __restrict__ A, const bf16* __restrict__ Bt,
    const float* __restrict__ bias, void* __restrict__ outv,
    int M, int N, int Kfull)
{
    constexpr int MR  = (BN == 128) ? 4 : 2;
    constexpr int ASZ = 128 * 32, BSZ = BN * 32;
    __shared__ bf16 As[2][ASZ];
    __shared__ bf16 Bs[2][BSZ];

    const int t    = threadIdx.x;
    const int lane = t & 63;
    const int w    = t >> 6;
    const int wm   = (BN == 128) ? (w >> 1) * 64 : w * 32;
    const int wn   = (BN == 128) ? (w & 1) * 64 : 0;
    const int kg   = lane >> 4, lr = lane & 15;

    const int nwg = gridDim.x;
    const int bid = (blockIdx.x & 7) * (nwg >> 3) + (blockIdx.x >> 3);
    const int nbn = N / BN, nbm = M / 128;
    const int ks  = (SK > 1) ? bid / (nbm * nbn) : 0;
    const int r   = (SK > 1) ? bid % (nbm * nbn) : bid;
    const int bm  = ((SK > 1) ? (r / nbn) : (r % nbm)) * 128;
    const int bn  = ((SK > 1) ? (r % nbn) : (r / nbm)) * BN;

    const int Ksl = Kfull / SK;
    const int kof = ks * Ksl;

    f32x4 acc[MR][4] = {};

    auto stage = [&](int buf, int k0) {
        #pragma unroll
        for (int c = 0; c < 2; ++c) {
            const int ci = c * 256 + t;
            gload_lds16(A + (size_t)(bm + (ci >> 2)) * Kfull + kof + k0 + (ci & 3) * 8,
                        &As[buf][ci * 8]);
        }
        #pragma unroll
        for (int c = 0; c < BN / 64; ++c) {
            const int ci = c * 256 + t;
            gload_lds16(Bt + (size_t)(bn + (ci >> 2)) * Kfull + kof + k0 + (ci & 3) * 8,
                        &Bs[buf][ci * 8]);
        }
    };

    stage(0, 0);
    __syncthreads();

    int cur = 0;
    for (int k0 = 0; k0 < Ksl; k0 += 32) {
        if (k0 + 32 < Ksl) stage(cur ^ 1, k0 + 32);

        bf16x8 af[MR], bfr[4];
        #pragma unroll
        for (int m = 0; m < MR; ++m)
            af[m] = *(const bf16x8*)(&As[cur][(wm + m * 16 + lr) * 32 + kg * 8]);
        #pragma unroll
        for (int n = 0; n < 4; ++n)
            bfr[n] = *(const bf16x8*)(&Bs[cur][(wn + n * 16 + lr) * 32 + kg * 8]);
        #pragma unroll
        for (int m = 0; m < MR; ++m)
            #pragma unroll
            for (int n = 0; n < 4; ++n)
                acc[m][n] = __builtin_amdgcn_mfma_f32_16x16x32_bf16(af[m], bfr[n], acc[m][n], 0, 0, 0);

        __syncthreads();
        cur ^= 1;
    }

    #pragma unroll
    for (int m = 0; m < MR; ++m) {
        const int row = bm + wm + m * 16 + kg * 4;
        #pragma unroll
        for (int n = 0; n < 4; ++n) {
            const int col = bn + wn + n * 16 + lr;
            #pragma unroll
            for (int j = 0; j < 4; ++j) {
                const float vv = acc[m][n][j];
                const size_t idx = (size_t)(row + j) * N + col;
                if (EPI == 0) {
                    ((bf16*)outv)[idx] = (bf16)vv;
                } else if (EPI == 1) {
                    const float z = vv + bias[col];
                    const float gl = 0.5f * z * (1.0f + erff(z * 0.70710678118654752f));
                    ((bf16*)outv)[idx] = (bf16)gl;
                } else {
                    ((float*)outv)[(size_t)ks * M * N + idx] = vv;
                }
            }
        }
    }
}

// ------------------------------------------------- MFMA flash attention
// dbuf K/V staging (issue-early/write-late), chunk-XOR-swizzled Vt,
// XCD-chunked 1-D grid (each XCD owns 4 heads -> K/V L2-resident).
__global__ __launch_bounds__(256) void attn_kernel(
    const bf16* __restrict__ qkv, bf16* __restrict__ od)
{
    __shared__ bf16 Ks[2][64][72];
    __shared__ bf16 Vt[2][64][64];   // [d][kv], 16B chunks XOR (row>>3)
    __shared__ bf16 Ps[64][72];      // wave-private rows

    const int nwg = gridDim.x;       // 512
    const int bid = (blockIdx.x & 7) * (nwg >> 3) + (blockIdx.x >> 3);
    const int q0  = (bid & 15) * 64;
    const int bh  = bid >> 4;
    const int b   = bh >> 4, h = bh & 15;
    const int t   = threadIdx.x, w = t >> 6, lane = t & 63;
    const int kg  = lane >> 4, lr = lane & 15;

    const bf16* qbase = qkv + (size_t)b * SEQ * QKVN + h * 64;
    const bf16* kbase = qbase + DIM;
    const bf16* vbase = qbase + 2 * DIM;

    bf16x8 qf0, qf1;
    {
        const bf16* qr = qbase + (size_t)(q0 + w * 16 + lr) * QKVN;
        qf0 = *(const bf16x8*)(qr + kg * 8);
        qf1 = *(const bf16x8*)(qr + 32 + kg * 8);
    }

    f32x4 o_acc[4] = {};
    float m_run[4] = {-1e30f, -1e30f, -1e30f, -1e30f};
    float l_run[4] = {};

    const int rK = t >> 3, oK = (t & 7) * 8;   // K stage rows rK, rK+32
    const int rp = t >> 3, cV = t & 7;         // V stage rows 2rp,2rp+1, d=cV*8..+8

    bf16x8 kr0, kr1, vr0, vr1;                 // in-flight staging regs
    auto loadKV = [&](int kb) {
        kr0 = *(const bf16x8*)(kbase + (size_t)(kb + rK) * QKVN + oK);
        kr1 = *(const bf16x8*)(kbase + (size_t)(kb + 32 + rK) * QKVN + oK);
        vr0 = *(const bf16x8*)(vbase + (size_t)(kb + 2 * rp) * QKVN + cV * 8);
        vr1 = *(const bf16x8*)(vbase + (size_t)(kb + 2 * rp + 1) * QKVN + cV * 8);
    };
    auto storeKV = [&](int buf) {
        *(bf16x8*)&Ks[buf][rK][oK]      = kr0;
        *(bf16x8*)&Ks[buf][32 + rK][oK] = kr1;
        const int inrow = (((rp >> 2) ^ cV) << 4) | ((rp << 2) & 15);
        #pragma unroll
        for (int j = 0; j < 8; ++j) {
            bf16x2 p; p[0] = vr0[j]; p[1] = vr1[j];
            *(bf16x2*)((char*)&Vt[buf][cV * 8 + j][0] + inrow) = p;
        }
    };

    loadKV(0);
    storeKV(0);
    __syncthreads();

    int cur = 0;
    for (int kb = 0; kb < SEQ; kb += 64) {
        const bool more = (kb + 64 < SEQ);
        if (more) loadKV(kb + 64);            // issue early: latency hides under compute

        f32x4 s[4] = {};
        #pragma unroll
        for (int n = 0; n < 4; ++n) {
            const bf16x8 kf0 = *(const bf16x8*)&Ks[cur][n * 16 + lr][kg * 8];
            const bf16x8 kf1 = *(const bf16x8*)&Ks[cur][n * 16 + lr][32 + kg * 8];
            s[n] = __builtin_amdgcn_mfma_f32_16x16x32_bf16(qf0, kf0, s[n], 0, 0, 0);
            s[n] = __builtin_amdgcn_mfma_f32_16x16x32_bf16(qf1, kf1, s[n], 0, 0, 0);
        }
        #pragma unroll
        for (int n = 0; n < 4; ++n) s[n] *= 0.125f;

        float corr[4], rs[4];
        #pragma unroll
        for (int j = 0; j < 4; ++j) {
            float mx = fmaxf(fmaxf(s[0][j], s[1][j]), fmaxf(s[2][j], s[3][j]));
            #pragma unroll
            for (int o = 1; o < 16; o <<= 1) mx = fmaxf(mx, __shfl_xor(mx, o, 64));
            const float mn = fmaxf(m_run[j], mx);
            corr[j] = __expf(m_run[j] - mn);
            m_run[j] = mn;
            rs[j] = 0.f;
        }
        #pragma unroll
        for (int n = 0; n < 4; ++n)
            #pragma unroll
            for (int j = 0; j < 4; ++j) {
                const float e = __expf(s[n][j] - m_run[j]);
                s[n][j] = e; rs[j] += e;
            }
        #pragma unroll
        for (int j = 0; j < 4; ++j) {
            #pragma unroll
            for (int o = 1; o < 16; o <<= 1) rs[j] += __shfl_xor(rs[j], o, 64);
            l_run[j] = l_run[j] * corr[j] + rs[j];
        }
        #pragma unroll
        for (int nd = 0; nd < 4; ++nd)
            #pragma unroll
            for (int j = 0; j < 4; ++j) o_acc[nd][j] *= corr[j];

        #pragma unroll
        for (int n = 0; n < 4; ++n)
            #pragma unroll
            for (int j = 0; j < 4; ++j)
                Ps[w * 16 + kg * 4 + j][n * 16 + lr] = (bf16)s[n][j];

        const bf16x8 pf0 = *(const bf16x8*)&Ps[w * 16 + lr][kg * 8];
        const bf16x8 pf1 = *(const bf16x8*)&Ps[w * 16 + lr][32 + kg * 8];
        #pragma unroll
        for (int nd = 0; nd < 4; ++nd) {
            const int row  = nd * 16 + lr;
            const int crow = (row >> 3) & 7;
            const bf16x8 vf0 = *(const bf16x8*)((const char*)&Vt[cur][row][0] + ((kg ^ crow) << 4));
            const bf16x8 vf1 = *(const bf16x8*)((const char*)&Vt[cur][row][0] + (((4 + kg) ^ crow) << 4));
            o_acc[nd] = __builtin_amdgcn_mfma_f32_16x16x32_bf16(pf0, vf0, o_acc[nd], 0, 0, 0);
            o_acc[nd] = __builtin_amdgcn_mfma_f32_16x16x32_bf16(pf1, vf1, o_acc[nd], 0, 0, 0);
        }

        if (more) storeKV(cur ^ 1);           // write-late into the other buffer
        __syncthreads();
        cur ^= 1;
    }

    float inv[4];
    #pragma unroll
    for (int j = 0; j < 4; ++j) inv[j] = 1.0f / l_run[j];
    bf16* ob = od + (size_t)(b * SEQ + q0 + w * 16 + kg * 4) * DIM + h * 64;
    #pragma unroll
    for (int nd = 0; nd < 4; ++nd)
        #pragma unroll
        for (int j = 0; j < 4; ++j)
            ob[(size_t)j * DIM + nd * 16 + lr] = (bf16)(o_acc[nd][j] * inv[j]);
}

// ---------------------------------------------------------------- launch
extern "C" void kernel_launch(void* const* d_in, const int* in_sizes, int n_in,
                              void* d_out, int out_size, void* d_ws, size_t ws_size,
                              hipStream_t stream)
{
    const float* x    = (const float*)d_in[0];
    const float* ln1w = (const float*)d_in[1];
    const float* ln1b = (const float*)d_in[2];
    const float* Wq   = (const float*)d_in[3];
    const float* Wk   = (const float*)d_in[4];
    const float* Wv   = (const float*)d_in[5];
    const float* Wo   = (const float*)d_in[6];
    const float* bo   = (const float*)d_in[7];
    const float* ln2w = (const float*)d_in[8];
    const float* ln2b = (const float*)d_in[9];
    const float* W1   = (const float*)d_in[10];
    const float* b1   = (const float*)d_in[11];
    const float* W2   = (const float*)d_in[12];
    const float* b2   = (const float*)d_in[13];

    char* ws = (char*)d_ws;
    float* xbuf  = (float*)(ws);                 // 8 MB f32 residual
    bf16*  hbuf  = (bf16*)(ws + (8ull  << 20));  // 4 MB
    bf16*  qkvb  = (bf16*)(ws + (12ull << 20));  // 12 MB
    bf16*  obuf  = (bf16*)(ws + (24ull << 20));  // 4 MB
    bf16*  gbuf  = (bf16*)(ws + (28ull << 20));  // 16 MB
    bf16*  wqkvt = (bf16*)(ws + (44ull << 20));  // 6 MB  [3072][1024]
    bf16*  wot   = (bf16*)(ws + (50ull << 20));  // 2 MB  [1024][1024]
    bf16*  w1t   = (bf16*)(ws + (52ull << 20));  // 8 MB  [4096][1024]
    bf16*  w2t   = (bf16*)(ws + (60ull << 20));  // 8 MB  [1024][4096]
    float* pbuf  = (float*)(ws + (68ull << 20)); // 16 MB [2][TOK][DIM] f32

    hipMemcpyAsync(xbuf, x, (size_t)TOK * DIM * sizeof(float),
                   hipMemcpyDeviceToDevice, stream);

    const size_t DD = (size_t)DIM * DIM, DF = (size_t)DIM * FF;
    for (int l = 0; l < LAYERS; ++l) {
        wtrans_all_kernel<<<12288, 256, 0, stream>>>(
            Wq + l * DD, Wk + l * DD, Wv + l * DD, Wo + l * DD,
            W1 + l * DF, W2 + l * DF, wqkvt, wot, w1t, w2t);

        if (l == 0)
            ln_kernel<<<TOK, 256, 0, stream>>>(xbuf, ln1w, ln1b, hbuf);
        // (l>0: hbuf already holds LN1 output from previous layer's lncomb)

        gemm_kernel<64, 0, 1><<<16 * 48, 256, 0, stream>>>(
            hbuf, wqkvt, nullptr, qkvb, TOK, QKVN, DIM);

        attn_kernel<<<512, 256, 0, stream>>>(qkvb, obuf);

        gemm_kernel<64, 3, 2><<<16 * 8 * 2 * 2, 256, 0, stream>>>(
            obuf, wot, nullptr, pbuf, TOK, DIM, DIM);

        lncomb_kernel<true><<<TOK, 256, 0, stream>>>(
            xbuf, pbuf, bo + l * DIM, ln2w + l * DIM, ln2b + l * DIM, hbuf);

        gemm_kernel<128, 1, 1><<<16 * 32, 256, 0, stream>>>(
            hbuf, w1t, b1 + l * FF, gbuf, TOK, FF, DIM);

        gemm_kernel<64, 3, 2><<<16 * 8 * 2 * 2, 256, 0, stream>>>(
            gbuf, w2t, nullptr, pbuf, TOK, DIM, FF);

        if (l + 1 < LAYERS)
            lncomb_kernel<true><<<TOK, 256, 0, stream>>>(
                xbuf, pbuf, b2 + l * DIM, ln1w + (l + 1) * DIM, ln1b + (l + 1) * DIM, hbuf);
        else
            lncomb_kernel<false><<<TOK, 256, 0, stream>>>(
                xbuf, pbuf, b2 + l * DIM, nullptr, nullptr, nullptr);
    }

    hipMemcpyAsync(d_out, xbuf, (size_t)TOK * DIM * sizeof(float),
                   hipMemcpyDeviceToDevice, stream);
}

// Round 6
// 650.486 us; speedup vs baseline: 3.6639x; 1.0891x over previous
//
#include <hip/hip_runtime.h>
#include <hip/hip_bf16.h>

using bf16   = __bf16;
using bf16x2 = __attribute__((ext_vector_type(2))) __bf16;
using bf16x4 = __attribute__((ext_vector_type(4))) __bf16;
using bf16x8 = __attribute__((ext_vector_type(8))) __bf16;
using f32x4  = __attribute__((ext_vector_type(4))) float;

constexpr int LAYERS = 4;
constexpr int BATCH  = 2;
constexpr int SEQ    = 1024;
constexpr int DIM    = 1024;
constexpr int FF     = 4096;
constexpr int HEADS  = 16;
constexpr int TOK    = BATCH * SEQ;   // 2048
constexpr int QKVN   = 3 * DIM;       // 3072
constexpr float EPS  = 1e-5f;

// async global->LDS, 16B per lane (HW: wave-uniform LDS base + lane*16)
__device__ __forceinline__ void gload_lds16(const void* g, void* l) {
    __builtin_amdgcn_global_load_lds(
        (const __attribute__((address_space(1))) void*)g,
        (__attribute__((address_space(3))) void*)l, 16, 0, 0);
}

// ---------------------------------------------------------------- LayerNorm
__global__ __launch_bounds__(256) void ln_kernel(
    const float* __restrict__ x, const float* __restrict__ g,
    const float* __restrict__ bt, bf16* __restrict__ out)
{
    __shared__ float red[8];
    const int row = blockIdx.x, t = threadIdx.x;
    const float4 v = ((const float4*)(x + (size_t)row * DIM))[t];

    float s = v.x + v.y + v.z + v.w;
    #pragma unroll
    for (int o = 32; o; o >>= 1) s += __shfl_down(s, o, 64);
    if ((t & 63) == 0) red[t >> 6] = s;
    __syncthreads();
    const float mean = (red[0] + red[1] + red[2] + red[3]) * (1.0f / DIM);

    const float dx = v.x - mean, dy = v.y - mean, dz = v.z - mean, dw = v.w - mean;
    float q = dx * dx + dy * dy + dz * dz + dw * dw;
    #pragma unroll
    for (int o = 32; o; o >>= 1) q += __shfl_down(q, o, 64);
    if ((t & 63) == 0) red[4 + (t >> 6)] = q;
    __syncthreads();
    const float var = (red[4] + red[5] + red[6] + red[7]) * (1.0f / DIM);
    const float rstd = rsqrtf(var + EPS);

    const float4 gg = ((const float4*)g)[t];
    const float4 bb = ((const float4*)bt)[t];
    bf16x4 o4;
    o4[0] = (bf16)(dx * rstd * gg.x + bb.x);
    o4[1] = (bf16)(dy * rstd * gg.y + bb.y);
    o4[2] = (bf16)(dz * rstd * gg.z + bb.z);
    o4[3] = (bf16)(dw * rstd * gg.w + bb.w);
    *(bf16x4*)(out + (size_t)row * DIM + t * 4) = o4;
}

// ------------------------------------- split-K combine (+bias) fused w/ LN
template<bool DO_LN>
__global__ __launch_bounds__(256) void lncomb_kernel(
    float* __restrict__ x, const float* __restrict__ p,
    const float* __restrict__ bias, const float* __restrict__ g,
    const float* __restrict__ bt, bf16* __restrict__ out)
{
    __shared__ float red[8];
    const int row = blockIdx.x, t = threadIdx.x;
    float4 v = ((const float4*)(x + (size_t)row * DIM))[t];
    const float4 a0 = ((const float4*)(p + (size_t)row * DIM))[t];
    const float4 a1 = ((const float4*)(p + (size_t)(TOK + row) * DIM))[t];
    const float4 bv = ((const float4*)bias)[t];
    v.x += a0.x + a1.x + bv.x;
    v.y += a0.y + a1.y + bv.y;
    v.z += a0.z + a1.z + bv.z;
    v.w += a0.w + a1.w + bv.w;
    ((float4*)(x + (size_t)row * DIM))[t] = v;
    if (!DO_LN) return;

    float s = v.x + v.y + v.z + v.w;
    #pragma unroll
    for (int o = 32; o; o >>= 1) s += __shfl_down(s, o, 64);
    if ((t & 63) == 0) red[t >> 6] = s;
    __syncthreads();
    const float mean = (red[0] + red[1] + red[2] + red[3]) * (1.0f / DIM);

    const float dx = v.x - mean, dy = v.y - mean, dz = v.z - mean, dw = v.w - mean;
    float q = dx * dx + dy * dy + dz * dz + dw * dw;
    #pragma unroll
    for (int o = 32; o; o >>= 1) q += __shfl_down(q, o, 64);
    if ((t & 63) == 0) red[4 + (t >> 6)] = q;
    __syncthreads();
    const float var = (red[4] + red[5] + red[6] + red[7]) * (1.0f / DIM);
    const float rstd = rsqrtf(var + EPS);

    const float4 gg = ((const float4*)g)[t];
    const float4 bb = ((const float4*)bt)[t];
    bf16x4 o4;
    o4[0] = (bf16)(dx * rstd * gg.x + bb.x);
    o4[1] = (bf16)(dy * rstd * gg.y + bb.y);
    o4[2] = (bf16)(dz * rstd * gg.z + bb.z);
    o4[3] = (bf16)(dw * rstd * gg.w + bb.w);
    *(bf16x4*)(out + (size_t)row * DIM + t * 4) = o4;
}

// ------------------------------ fused weight transpose+convert (one layer)
__global__ __launch_bounds__(256) void wtrans_all_kernel(
    const float* __restrict__ Wq, const float* __restrict__ Wk,
    const float* __restrict__ Wv, const float* __restrict__ Wo,
    const float* __restrict__ W1, const float* __restrict__ W2,
    bf16* __restrict__ wqkvt, bf16* __restrict__ wot,
    bf16* __restrict__ w1t, bf16* __restrict__ w2t)
{
    __shared__ float tile[32][33];
    const int bid = blockIdx.x;
    const float* W; bf16* Wt; int N, K, rowoff, bx, by;
    if (bid < 3072) {
        const int seg = bid >> 10, r = bid & 1023;
        W = (seg == 0) ? Wq : (seg == 1) ? Wk : Wv;
        Wt = wqkvt; N = DIM; K = DIM; rowoff = seg * DIM;
        bx = r & 31; by = r >> 5;
    } else if (bid < 4096) {
        const int r = bid - 3072;
        W = Wo; Wt = wot; N = DIM; K = DIM; rowoff = 0;
        bx = r & 31; by = r >> 5;
    } else if (bid < 8192) {
        const int r = bid - 4096;
        W = W1; Wt = w1t; N = FF; K = DIM; rowoff = 0;
        bx = r & 127; by = r >> 7;
    } else {
        const int r = bid - 8192;
        W = W2; Wt = w2t; N = DIM; K = FF; rowoff = 0;
        bx = r & 31; by = r >> 5;
    }
    const int bn = bx * 32, bk = by * 32;
    const int r = threadIdx.x >> 3, c4 = (threadIdx.x & 7) * 4;
    const float4 v = *(const float4*)(W + (size_t)(bk + r) * N + bn + c4);
    tile[r][c4 + 0] = v.x; tile[r][c4 + 1] = v.y;
    tile[r][c4 + 2] = v.z; tile[r][c4 + 3] = v.w;
    __syncthreads();
    bf16x4 o;
    #pragma unroll
    for (int j = 0; j < 4; ++j) o[j] = (bf16)tile[c4 + j][r];
    *(bf16x4*)(Wt + (size_t)(rowoff + bn + r) * K + bk + c4) = o;
}

// ---------------------------------------------------------------- GEMM
template<int BN, int EPI, int SK>
__global__ __launch_bounds__(256) void gemm_kernel(
    const bf16* __restrict__ A, const bf16* __restrict__ Bt,
    const float* __restrict__ bias, void* __restrict__ outv,
    int M, int N, int Kfull)
{
    constexpr int MR  = (BN == 128) ? 4 : 2;
    constexpr int ASZ = 128 * 32, BSZ = BN * 32;
    __shared__ bf16 As[2][ASZ];
    __shared__ bf16 Bs[2][BSZ];

    const int t    = threadIdx.x;
    const int lane = t & 63;
    const int w    = t >> 6;
    const int wm   = (BN == 128) ? (w >> 1) * 64 : w * 32;
    const int wn   = (BN == 128) ? (w & 1) * 64 : 0;
    const int kg   = lane >> 4, lr = lane & 15;

    const int nwg = gridDim.x;
    const int bid = (blockIdx.x & 7) * (nwg >> 3) + (blockIdx.x >> 3);
    const int nbn = N / BN, nbm = M / 128;
    const int ks  = (SK > 1) ? bid / (nbm * nbn) : 0;
    const int r   = (SK > 1) ? bid % (nbm * nbn) : bid;
    const int bm  = ((SK > 1) ? (r / nbn) : (r % nbm)) * 128;
    const int bn  = ((SK > 1) ? (r % nbn) : (r / nbm)) * BN;

    const int Ksl = Kfull / SK;
    const int kof = ks * Ksl;

    f32x4 acc[MR][4] = {};

    auto stage = [&](int buf, int k0) {
        #pragma unroll
        for (int c = 0; c < 2; ++c) {
            const int ci = c * 256 + t;
            gload_lds16(A + (size_t)(bm + (ci >> 2)) * Kfull + kof + k0 + (ci & 3) * 8,
                        &As[buf][ci * 8]);
        }
        #pragma unroll
        for (int c = 0; c < BN / 64; ++c) {
            const int ci = c * 256 + t;
            gload_lds16(Bt + (size_t)(bn + (ci >> 2)) * Kfull + kof + k0 + (ci & 3) * 8,
                        &Bs[buf][ci * 8]);
        }
    };

    stage(0, 0);
    __syncthreads();

    int cur = 0;
    for (int k0 = 0; k0 < Ksl; k0 += 32) {
        if (k0 + 32 < Ksl) stage(cur ^ 1, k0 + 32);

        bf16x8 af[MR], bfr[4];
        #pragma unroll
        for (int m = 0; m < MR; ++m)
            af[m] = *(const bf16x8*)(&As[cur][(wm + m * 16 + lr) * 32 + kg * 8]);
        #pragma unroll
        for (int n = 0; n < 4; ++n)
            bfr[n] = *(const bf16x8*)(&Bs[cur][(wn + n * 16 + lr) * 32 + kg * 8]);
        #pragma unroll
        for (int m = 0; m < MR; ++m)
            #pragma unroll
            for (int n = 0; n < 4; ++n)
                acc[m][n] = __builtin_amdgcn_mfma_f32_16x16x32_bf16(af[m], bfr[n], acc[m][n], 0, 0, 0);

        __syncthreads();
        cur ^= 1;
    }

    #pragma unroll
    for (int m = 0; m < MR; ++m) {
        const int row = bm + wm + m * 16 + kg * 4;
        #pragma unroll
        for (int n = 0; n < 4; ++n) {
            const int col = bn + wn + n * 16 + lr;
            #pragma unroll
            for (int j = 0; j < 4; ++j) {
                const float vv = acc[m][n][j];
                const size_t idx = (size_t)(row + j) * N + col;
                if (EPI == 0) {
                    ((bf16*)outv)[idx] = (bf16)vv;
                } else if (EPI == 1) {
                    const float z = vv + bias[col];
                    const float gl = 0.5f * z * (1.0f + erff(z * 0.70710678118654752f));
                    ((bf16*)outv)[idx] = (bf16)gl;
                } else {
                    ((float*)outv)[(size_t)ks * M * N + idx] = vv;
                }
            }
        }
    }
}

// ------------------------------------------------- MFMA flash attention
// Swapped-operand scheme: S^T = mfma(K,Q) -> per-lane softmax (q = lane&15),
// P row-major in LDS (b64 writes), O^T = mfma(V^T, P).  Vt chunk-XOR
// involution swizzle key=(d^(d>>3))&7: writes 2-way free, reads even.
__global__ __launch_bounds__(256) void attn_kernel(
    const bf16* __restrict__ qkv, bf16* __restrict__ od)
{
    __shared__ bf16 Ks[2][64][72];
    __shared__ bf16 Vt[2][64][64];   // [d][kv] physical, chunk-swizzled
    __shared__ bf16 Ps[4][16][72];   // per-wave P rows [q][kv]

    const int nwg = gridDim.x;       // 512
    const int bid = (blockIdx.x & 7) * (nwg >> 3) + (blockIdx.x >> 3);
    const int q0  = (bid & 15) * 64;
    const int bh  = bid >> 4;
    const int b   = bh >> 4, h = bh & 15;
    const int t   = threadIdx.x, w = t >> 6, lane = t & 63;
    const int kg  = lane >> 4, lr = lane & 15;

    const bf16* qbase = qkv + (size_t)b * SEQ * QKVN + h * 64;
    const bf16* kbase = qbase + DIM;
    const bf16* vbase = qbase + 2 * DIM;

    // Q fragment (wave's 16 rows), pre-scaled by 1/sqrt(64)=2^-3 (exact)
    bf16x8 qf0, qf1;
    {
        const bf16* qr = qbase + (size_t)(q0 + w * 16 + lr) * QKVN;
        qf0 = *(const bf16x8*)(qr + kg * 8);
        qf1 = *(const bf16x8*)(qr + 32 + kg * 8);
        #pragma unroll
        for (int j = 0; j < 8; ++j) {
            qf0[j] = (bf16)((float)qf0[j] * 0.125f);
            qf1[j] = (bf16)((float)qf1[j] * 0.125f);
        }
    }

    f32x4 o_acc[4] = {};
    float m_run = -1e30f, l_run = 0.f;

    const int rK = t >> 3, oK = (t & 7) * 8;   // K stage rows rK, rK+32
    const int rp = t >> 3, cV = t & 7;         // V stage rows 2rp,2rp+1

    bf16x8 kr0, kr1, vr0, vr1;
    auto loadKV = [&](int kb) {
        kr0 = *(const bf16x8*)(kbase + (size_t)(kb + rK) * QKVN + oK);
        kr1 = *(const bf16x8*)(kbase + (size_t)(kb + 32 + rK) * QKVN + oK);
        vr0 = *(const bf16x8*)(vbase + (size_t)(kb + 2 * rp) * QKVN + cV * 8);
        vr1 = *(const bf16x8*)(vbase + (size_t)(kb + 2 * rp + 1) * QKVN + cV * 8);
    };
    auto storeKV = [&](int buf) {
        *(bf16x8*)&Ks[buf][rK][oK]      = kr0;
        *(bf16x8*)&Ks[buf][32 + rK][oK] = kr1;
        #pragma unroll
        for (int j = 0; j < 8; ++j) {
            bf16x2 p; p[0] = vr0[j]; p[1] = vr1[j];
            const int d  = cV * 8 + j;
            const int dw = (((rp >> 2) ^ (j ^ cV)) << 2) | (rp & 3);
            *(bf16x2*)((char*)&Vt[buf][d][0] + dw * 4) = p;
        }
    };

    loadKV(0);
    storeKV(0);
    __syncthreads();

    int cur = 0;
    for (int kb = 0; kb < SEQ; kb += 64) {
        const bool more = (kb + 64 < SEQ);
        if (more) loadKV(kb + 64);            // issue early

        // ---- S^T = K·Q^T: lane holds 16 scores of q-row (q0+w*16+lr)
        f32x4 s[4] = {};
        #pragma unroll
        for (int n = 0; n < 4; ++n) {
            const bf16x8 kf0 = *(const bf16x8*)&Ks[cur][n * 16 + lr][kg * 8];
            const bf16x8 kf1 = *(const bf16x8*)&Ks[cur][n * 16 + lr][32 + kg * 8];
            s[n] = __builtin_amdgcn_mfma_f32_16x16x32_bf16(kf0, qf0, s[n], 0, 0, 0);
            s[n] = __builtin_amdgcn_mfma_f32_16x16x32_bf16(kf1, qf1, s[n], 0, 0, 0);
        }

        // ---- per-lane online softmax (2 shuffle steps across kg groups)
        float pmax = -1e30f;
        #pragma unroll
        for (int n = 0; n < 4; ++n)
            #pragma unroll
            for (int j = 0; j < 4; ++j) pmax = fmaxf(pmax, s[n][j]);
        pmax = fmaxf(pmax, __shfl_xor(pmax, 16, 64));
        pmax = fmaxf(pmax, __shfl_xor(pmax, 32, 64));

        if (!__all(pmax <= m_run + 8.0f)) {   // defer-max (exact)
            const float mn   = fmaxf(m_run, pmax);
            const float corr = __expf(m_run - mn);
            m_run = mn;
            l_run *= corr;
            #pragma unroll
            for (int nd = 0; nd < 4; ++nd)
                #pragma unroll
                for (int j = 0; j < 4; ++j) o_acc[nd][j] *= corr;
        }

        float rs = 0.f;
        #pragma unroll
        for (int n = 0; n < 4; ++n)
            #pragma unroll
            for (int j = 0; j < 4; ++j) {
                const float e = __expf(s[n][j] - m_run);
                s[n][j] = e; rs += e;
            }
        rs += __shfl_xor(rs, 16, 64);
        rs += __shfl_xor(rs, 32, 64);
        l_run += rs;

        // ---- P -> LDS row-major (b64 writes, 2-way free)
        #pragma unroll
        for (int n = 0; n < 4; ++n) {
            bf16x4 pw;
            #pragma unroll
            for (int j = 0; j < 4; ++j) pw[j] = (bf16)s[n][j];
            *(bf16x4*)&Ps[w][lr][n * 16 + kg * 4] = pw;
        }

        // ---- O^T += V^T · P  (A = V^T frag, B = P frag)
        const bf16x8 pf0 = *(const bf16x8*)&Ps[w][lr][kg * 8];
        const bf16x8 pf1 = *(const bf16x8*)&Ps[w][lr][32 + kg * 8];
        #pragma unroll
        for (int nd = 0; nd < 4; ++nd) {
            const int d   = nd * 16 + lr;
            const int key = (d ^ (d >> 3)) & 7;
            const bf16x8 vf0 = *(const bf16x8*)((const char*)&Vt[cur][d][0] + ((kg ^ key) << 4));
            const bf16x8 vf1 = *(const bf16x8*)((const char*)&Vt[cur][d][0] + (((4 + kg) ^ key) << 4));
            o_acc[nd] = __builtin_amdgcn_mfma_f32_16x16x32_bf16(vf0, pf0, o_acc[nd], 0, 0, 0);
            o_acc[nd] = __builtin_amdgcn_mfma_f32_16x16x32_bf16(vf1, pf1, o_acc[nd], 0, 0, 0);
        }

        if (more) storeKV(cur ^ 1);           // write late
        __syncthreads();
        cur ^= 1;
    }

    // ---- finalize: O[q][d], q = q0+w*16+lr, d = nd*16+kg*4+j
    const float inv = 1.0f / l_run;
    bf16* ob = od + (size_t)(b * SEQ + q0 + w * 16 + lr) * DIM + h * 64;
    #pragma unroll
    for (int nd = 0; nd < 4; ++nd) {
        bf16x4 o4;
        #pragma unroll
        for (int j = 0; j < 4; ++j) o4[j] = (bf16)(o_acc[nd][j] * inv);
        *(bf16x4*)(ob + nd * 16 + kg * 4) = o4;
    }
}

// ---------------------------------------------------------------- launch
extern "C" void kernel_launch(void* const* d_in, const int* in_sizes, int n_in,
                              void* d_out, int out_size, void* d_ws, size_t ws_size,
                              hipStream_t stream)
{
    const float* x    = (const float*)d_in[0];
    const float* ln1w = (const float*)d_in[1];
    const float* ln1b = (const float*)d_in[2];
    const float* Wq   = (const float*)d_in[3];
    const float* Wk   = (const float*)d_in[4];
    const float* Wv   = (const float*)d_in[5];
    const float* Wo   = (const float*)d_in[6];
    const float* bo   = (const float*)d_in[7];
    const float* ln2w = (const float*)d_in[8];
    const float* ln2b = (const float*)d_in[9];
    const float* W1   = (const float*)d_in[10];
    const float* b1   = (const float*)d_in[11];
    const float* W2   = (const float*)d_in[12];
    const float* b2   = (const float*)d_in[13];

    char* ws = (char*)d_ws;
    float* xbuf  = (float*)(ws);                 // 8 MB f32 residual
    bf16*  hbuf  = (bf16*)(ws + (8ull  << 20));  // 4 MB
    bf16*  qkvb  = (bf16*)(ws + (12ull << 20));  // 12 MB
    bf16*  obuf  = (bf16*)(ws + (24ull << 20));  // 4 MB
    bf16*  gbuf  = (bf16*)(ws + (28ull << 20));  // 16 MB
    bf16*  wqkvt = (bf16*)(ws + (44ull << 20));  // 6 MB  [3072][1024]
    bf16*  wot   = (bf16*)(ws + (50ull << 20));  // 2 MB  [1024][1024]
    bf16*  w1t   = (bf16*)(ws + (52ull << 20));  // 8 MB  [4096][1024]
    bf16*  w2t   = (bf16*)(ws + (60ull << 20));  // 8 MB  [1024][4096]
    float* pbuf  = (float*)(ws + (68ull << 20)); // 16 MB [2][TOK][DIM] f32

    hipMemcpyAsync(xbuf, x, (size_t)TOK * DIM * sizeof(float),
                   hipMemcpyDeviceToDevice, stream);

    const size_t DD = (size_t)DIM * DIM, DF = (size_t)DIM * FF;
    for (int l = 0; l < LAYERS; ++l) {
        wtrans_all_kernel<<<12288, 256, 0, stream>>>(
            Wq + l * DD, Wk + l * DD, Wv + l * DD, Wo + l * DD,
            W1 + l * DF, W2 + l * DF, wqkvt, wot, w1t, w2t);

        if (l == 0)
            ln_kernel<<<TOK, 256, 0, stream>>>(xbuf, ln1w, ln1b, hbuf);

        gemm_kernel<64, 0, 1><<<16 * 48, 256, 0, stream>>>(
            hbuf, wqkvt, nullptr, qkvb, TOK, QKVN, DIM);

        attn_kernel<<<512, 256, 0, stream>>>(qkvb, obuf);

        gemm_kernel<64, 3, 2><<<16 * 8 * 2 * 2, 256, 0, stream>>>(
            obuf, wot, nullptr, pbuf, TOK, DIM, DIM);

        lncomb_kernel<true><<<TOK, 256, 0, stream>>>(
            xbuf, pbuf, bo + l * DIM, ln2w + l * DIM, ln2b + l * DIM, hbuf);

        gemm_kernel<128, 1, 1><<<16 * 32, 256, 0, stream>>>(
            hbuf, w1t, b1 + l * FF, gbuf, TOK, FF, DIM);

        gemm_kernel<64, 3, 2><<<16 * 8 * 2 * 2, 256, 0, stream>>>(
            gbuf, w2t, nullptr, pbuf, TOK, DIM, FF);

        if (l + 1 < LAYERS)
            lncomb_kernel<true><<<TOK, 256, 0, stream>>>(
                xbuf, pbuf, b2 + l * DIM, ln1w + (l + 1) * DIM, ln1b + (l + 1) * DIM, hbuf);
        else
            lncomb_kernel<false><<<TOK, 256, 0, stream>>>(
                xbuf, pbuf, b2 + l * DIM, nullptr, nullptr, nullptr);
    }

    hipMemcpyAsync(d_out, xbuf, (size_t)TOK * DIM * sizeof(float),
                   hipMemcpyDeviceToDevice, stream);
}

// Round 7
// 607.149 us; speedup vs baseline: 3.9255x; 1.0714x over previous
//
#include <hip/hip_runtime.h>
#include <hip/hip_bf16.h>

using bf16   = __bf16;
using bf16x2 = __attribute__((ext_vector_type(2))) __bf16;
using bf16x4 = __attribute__((ext_vector_type(4))) __bf16;
using bf16x8 = __attribute__((ext_vector_type(8))) __bf16;
using f32x4  = __attribute__((ext_vector_type(4))) float;

constexpr int LAYERS = 4;
constexpr int BATCH  = 2;
constexpr int SEQ    = 1024;
constexpr int DIM    = 1024;
constexpr int FF     = 4096;
constexpr int HEADS  = 16;
constexpr int TOK    = BATCH * SEQ;   // 2048
constexpr int QKVN   = 3 * DIM;       // 3072
constexpr float EPS  = 1e-5f;

// async global->LDS, 16B per lane (HW: wave-uniform LDS base + lane*16)
__device__ __forceinline__ void gload_lds16(const void* g, void* l) {
    __builtin_amdgcn_global_load_lds(
        (const __attribute__((address_space(1))) void*)g,
        (__attribute__((address_space(3))) void*)l, 16, 0, 0);
}

// ---------------------------------------------------------------- LayerNorm
__global__ __launch_bounds__(256) void ln_kernel(
    const float* __restrict__ x, const float* __restrict__ g,
    const float* __restrict__ bt, bf16* __restrict__ out)
{
    __shared__ float red[8];
    const int row = blockIdx.x, t = threadIdx.x;
    const float4 v = ((const float4*)(x + (size_t)row * DIM))[t];

    float s = v.x + v.y + v.z + v.w;
    #pragma unroll
    for (int o = 32; o; o >>= 1) s += __shfl_down(s, o, 64);
    if ((t & 63) == 0) red[t >> 6] = s;
    __syncthreads();
    const float mean = (red[0] + red[1] + red[2] + red[3]) * (1.0f / DIM);

    const float dx = v.x - mean, dy = v.y - mean, dz = v.z - mean, dw = v.w - mean;
    float q = dx * dx + dy * dy + dz * dz + dw * dw;
    #pragma unroll
    for (int o = 32; o; o >>= 1) q += __shfl_down(q, o, 64);
    if ((t & 63) == 0) red[4 + (t >> 6)] = q;
    __syncthreads();
    const float var = (red[4] + red[5] + red[6] + red[7]) * (1.0f / DIM);
    const float rstd = rsqrtf(var + EPS);

    const float4 gg = ((const float4*)g)[t];
    const float4 bb = ((const float4*)bt)[t];
    bf16x4 o4;
    o4[0] = (bf16)(dx * rstd * gg.x + bb.x);
    o4[1] = (bf16)(dy * rstd * gg.y + bb.y);
    o4[2] = (bf16)(dz * rstd * gg.z + bb.z);
    o4[3] = (bf16)(dw * rstd * gg.w + bb.w);
    *(bf16x4*)(out + (size_t)row * DIM + t * 4) = o4;
}

// ------------------------------------- split-K combine (+bias) fused w/ LN
template<bool DO_LN>
__global__ __launch_bounds__(256) void lncomb_kernel(
    float* __restrict__ x, const float* __restrict__ p,
    const float* __restrict__ bias, const float* __restrict__ g,
    const float* __restrict__ bt, bf16* __restrict__ out)
{
    __shared__ float red[8];
    const int row = blockIdx.x, t = threadIdx.x;
    float4 v = ((const float4*)(x + (size_t)row * DIM))[t];
    const float4 a0 = ((const float4*)(p + (size_t)row * DIM))[t];
    const float4 a1 = ((const float4*)(p + (size_t)(TOK + row) * DIM))[t];
    const float4 bv = ((const float4*)bias)[t];
    v.x += a0.x + a1.x + bv.x;
    v.y += a0.y + a1.y + bv.y;
    v.z += a0.z + a1.z + bv.z;
    v.w += a0.w + a1.w + bv.w;
    ((float4*)(x + (size_t)row * DIM))[t] = v;
    if (!DO_LN) return;

    float s = v.x + v.y + v.z + v.w;
    #pragma unroll
    for (int o = 32; o; o >>= 1) s += __shfl_down(s, o, 64);
    if ((t & 63) == 0) red[t >> 6] = s;
    __syncthreads();
    const float mean = (red[0] + red[1] + red[2] + red[3]) * (1.0f / DIM);

    const float dx = v.x - mean, dy = v.y - mean, dz = v.z - mean, dw = v.w - mean;
    float q = dx * dx + dy * dy + dz * dz + dw * dw;
    #pragma unroll
    for (int o = 32; o; o >>= 1) q += __shfl_down(q, o, 64);
    if ((t & 63) == 0) red[4 + (t >> 6)] = q;
    __syncthreads();
    const float var = (red[4] + red[5] + red[6] + red[7]) * (1.0f / DIM);
    const float rstd = rsqrtf(var + EPS);

    const float4 gg = ((const float4*)g)[t];
    const float4 bb = ((const float4*)bt)[t];
    bf16x4 o4;
    o4[0] = (bf16)(dx * rstd * gg.x + bb.x);
    o4[1] = (bf16)(dy * rstd * gg.y + bb.y);
    o4[2] = (bf16)(dz * rstd * gg.z + bb.z);
    o4[3] = (bf16)(dw * rstd * gg.w + bb.w);
    *(bf16x4*)(out + (size_t)row * DIM + t * 4) = o4;
}

// ------------------------------ fused weight transpose+convert (one layer)
__global__ __launch_bounds__(256) void wtrans_all_kernel(
    const float* __restrict__ Wq, const float* __restrict__ Wk,
    const float* __restrict__ Wv, const float* __restrict__ Wo,
    const float* __restrict__ W1, const float* __restrict__ W2,
    bf16* __restrict__ wqkvt, bf16* __restrict__ wot,
    bf16* __restrict__ w1t, bf16* __restrict__ w2t)
{
    __shared__ float tile[32][33];
    const int bid = blockIdx.x;
    const float* W; bf16* Wt; int N, K, rowoff, bx, by;
    if (bid < 3072) {
        const int seg = bid >> 10, r = bid & 1023;
        W = (seg == 0) ? Wq : (seg == 1) ? Wk : Wv;
        Wt = wqkvt; N = DIM; K = DIM; rowoff = seg * DIM;
        bx = r & 31; by = r >> 5;
    } else if (bid < 4096) {
        const int r = bid - 3072;
        W = Wo; Wt = wot; N = DIM; K = DIM; rowoff = 0;
        bx = r & 31; by = r >> 5;
    } else if (bid < 8192) {
        const int r = bid - 4096;
        W = W1; Wt = w1t; N = FF; K = DIM; rowoff = 0;
        bx = r & 127; by = r >> 7;
    } else {
        const int r = bid - 8192;
        W = W2; Wt = w2t; N = DIM; K = FF; rowoff = 0;
        bx = r & 31; by = r >> 5;
    }
    const int bn = bx * 32, bk = by * 32;
    const int r = threadIdx.x >> 3, c4 = (threadIdx.x & 7) * 4;
    const float4 v = *(const float4*)(W + (size_t)(bk + r) * N + bn + c4);
    tile[r][c4 + 0] = v.x; tile[r][c4 + 1] = v.y;
    tile[r][c4 + 2] = v.z; tile[r][c4 + 3] = v.w;
    __syncthreads();
    bf16x4 o;
    #pragma unroll
    for (int j = 0; j < 4; ++j) o[j] = (bf16)tile[c4 + j][r];
    *(bf16x4*)(Wt + (size_t)(rowoff + bn + r) * K + bk + c4) = o;
}

// ---------------------------------------------------------------- GEMM
// C = A[M,Kfull](bf16) @ Bt(bf16 [N][Kfull]).  BM=128, BN=64, BK=64,
// dbuf LDS, both-sides XOR chunk swizzle (key = row&7) -> conflict-free
// ds_read_b128.  SK-way split-K.  EPI 0: bf16. 1: +bias GELU bf16.
// 3: f32 partial at outv[ks*M*N].
template<int EPI, int SK>
__global__ __launch_bounds__(256) void gemm_kernel(
    const bf16* __restrict__ A, const bf16* __restrict__ Bt,
    const float* __restrict__ bias, void* __restrict__ outv,
    int M, int N, int Kfull)
{
    constexpr int MR = 2;
    __shared__ bf16 As[2][128 * 64];
    __shared__ bf16 Bs[2][64 * 64];

    const int t    = threadIdx.x;
    const int lane = t & 63;
    const int w    = t >> 6;
    const int wm   = w * 32;
    const int kg   = lane >> 4, lr = lane & 15;
    const int key  = lr & 7;

    const int nwg = gridDim.x;
    const int bid = (blockIdx.x & 7) * (nwg >> 3) + (blockIdx.x >> 3);
    const int nbn = N / 64, nbm = M / 128;
    const int ks  = (SK > 1) ? bid / (nbm * nbn) : 0;
    const int r   = (SK > 1) ? bid % (nbm * nbn) : bid;
    const int bm  = ((SK > 1) ? (r / nbn) : (r % nbm)) * 128;
    const int bn  = ((SK > 1) ? (r % nbn) : (r / nbm)) * 64;

    const int Ksl = Kfull / SK;
    const int kof = ks * Ksl;

    f32x4 acc[MR][4] = {};

    // stage: logical LDS chunk (row, c) holds global k-chunk (c ^ (row&7))
    auto stage = [&](int buf, int k0) {
        #pragma unroll
        for (int it = 0; it < 4; ++it) {
            const int ci = it * 256 + t, row = ci >> 3, c = ci & 7;
            gload_lds16(A + (size_t)(bm + row) * Kfull + kof + k0 + ((c ^ (row & 7)) << 3),
                        &As[buf][ci * 8]);
        }
        #pragma unroll
        for (int it = 0; it < 2; ++it) {
            const int ci = it * 256 + t, row = ci >> 3, c = ci & 7;
            gload_lds16(Bt + (size_t)(bn + row) * Kfull + kof + k0 + ((c ^ (row & 7)) << 3),
                        &Bs[buf][ci * 8]);
        }
    };

    stage(0, 0);
    __syncthreads();

    int cur = 0;
    for (int k0 = 0; k0 < Ksl; k0 += 64) {
        if (k0 + 64 < Ksl) stage(cur ^ 1, k0 + 64);

        #pragma unroll
        for (int kk = 0; kk < 2; ++kk) {
            bf16x8 af[MR], bfr[4];
            #pragma unroll
            for (int m = 0; m < MR; ++m) {
                const int row = wm + m * 16 + lr;
                af[m] = *(const bf16x8*)(&As[cur][row * 64 + (((kk * 4 + kg) ^ key) << 3)]);
            }
            #pragma unroll
            for (int n = 0; n < 4; ++n) {
                const int row = n * 16 + lr;
                bfr[n] = *(const bf16x8*)(&Bs[cur][row * 64 + (((kk * 4 + kg) ^ key) << 3)]);
            }
            #pragma unroll
            for (int m = 0; m < MR; ++m)
                #pragma unroll
                for (int n = 0; n < 4; ++n)
                    acc[m][n] = __builtin_amdgcn_mfma_f32_16x16x32_bf16(af[m], bfr[n], acc[m][n], 0, 0, 0);
        }

        __syncthreads();
        cur ^= 1;
    }

    #pragma unroll
    for (int m = 0; m < MR; ++m) {
        const int row = bm + wm + m * 16 + kg * 4;
        #pragma unroll
        for (int n = 0; n < 4; ++n) {
            const int col = bn + n * 16 + lr;
            #pragma unroll
            for (int j = 0; j < 4; ++j) {
                const float vv = acc[m][n][j];
                const size_t idx = (size_t)(row + j) * N + col;
                if (EPI == 0) {
                    ((bf16*)outv)[idx] = (bf16)vv;
                } else if (EPI == 1) {
                    const float z = vv + bias[col];
                    const float gl = 0.5f * z * (1.0f + erff(z * 0.70710678118654752f));
                    ((bf16*)outv)[idx] = (bf16)gl;
                } else {
                    ((float*)outv)[(size_t)ks * M * N + idx] = vv;
                }
            }
        }
    }
}

// ------------------------------------------------- MFMA flash attention
// Swapped-operand scheme: S^T = mfma(K,Q) -> per-lane softmax (q = lane&15),
// P row-major in LDS (b64 writes), O^T = mfma(V^T, P).
__global__ __launch_bounds__(256) void attn_kernel(
    const bf16* __restrict__ qkv, bf16* __restrict__ od)
{
    __shared__ bf16 Ks[2][64][72];
    __shared__ bf16 Vt[2][64][64];   // [d][kv] physical, chunk-swizzled
    __shared__ bf16 Ps[4][16][72];   // per-wave P rows [q][kv]

    const int nwg = gridDim.x;       // 512
    const int bid = (blockIdx.x & 7) * (nwg >> 3) + (blockIdx.x >> 3);
    const int q0  = (bid & 15) * 64;
    const int bh  = bid >> 4;
    const int b   = bh >> 4, h = bh & 15;
    const int t   = threadIdx.x, w = t >> 6, lane = t & 63;
    const int kg  = lane >> 4, lr = lane & 15;

    const bf16* qbase = qkv + (size_t)b * SEQ * QKVN + h * 64;
    const bf16* kbase = qbase + DIM;
    const bf16* vbase = qbase + 2 * DIM;

    // Q fragment (wave's 16 rows), pre-scaled by 1/sqrt(64)=2^-3 (exact)
    bf16x8 qf0, qf1;
    {
        const bf16* qr = qbase + (size_t)(q0 + w * 16 + lr) * QKVN;
        qf0 = *(const bf16x8*)(qr + kg * 8);
        qf1 = *(const bf16x8*)(qr + 32 + kg * 8);
        #pragma unroll
        for (int j = 0; j < 8; ++j) {
            qf0[j] = (bf16)((float)qf0[j] * 0.125f);
            qf1[j] = (bf16)((float)qf1[j] * 0.125f);
        }
    }

    f32x4 o_acc[4] = {};
    float m_run = -1e30f, l_run = 0.f;

    const int rK = t >> 3, oK = (t & 7) * 8;   // K stage rows rK, rK+32
    const int rp = t >> 3, cV = t & 7;         // V stage rows 2rp,2rp+1

    bf16x8 kr0, kr1, vr0, vr1;
    auto loadKV = [&](int kb) {
        kr0 = *(const bf16x8*)(kbase + (size_t)(kb + rK) * QKVN + oK);
        kr1 = *(const bf16x8*)(kbase + (size_t)(kb + 32 + rK) * QKVN + oK);
        vr0 = *(const bf16x8*)(vbase + (size_t)(kb + 2 * rp) * QKVN + cV * 8);
        vr1 = *(const bf16x8*)(vbase + (size_t)(kb + 2 * rp + 1) * QKVN + cV * 8);
    };
    auto storeKV = [&](int buf) {
        *(bf16x8*)&Ks[buf][rK][oK]      = kr0;
        *(bf16x8*)&Ks[buf][32 + rK][oK] = kr1;
        #pragma unroll
        for (int j = 0; j < 8; ++j) {
            bf16x2 p; p[0] = vr0[j]; p[1] = vr1[j];
            const int d  = cV * 8 + j;
            const int dw = (((rp >> 2) ^ (j ^ cV)) << 2) | (rp & 3);
            *(bf16x2*)((char*)&Vt[buf][d][0] + dw * 4) = p;
        }
    };

    loadKV(0);
    storeKV(0);
    __syncthreads();

    int cur = 0;
    for (int kb = 0; kb < SEQ; kb += 64) {
        const bool more = (kb + 64 < SEQ);
        if (more) loadKV(kb + 64);            // issue early

        // ---- S^T = K·Q^T: lane holds 16 scores of q-row (q0+w*16+lr)
        f32x4 s[4] = {};
        __builtin_amdgcn_s_setprio(1);
        #pragma unroll
        for (int n = 0; n < 4; ++n) {
            const bf16x8 kf0 = *(const bf16x8*)&Ks[cur][n * 16 + lr][kg * 8];
            const bf16x8 kf1 = *(const bf16x8*)&Ks[cur][n * 16 + lr][32 + kg * 8];
            s[n] = __builtin_amdgcn_mfma_f32_16x16x32_bf16(kf0, qf0, s[n], 0, 0, 0);
            s[n] = __builtin_amdgcn_mfma_f32_16x16x32_bf16(kf1, qf1, s[n], 0, 0, 0);
        }
        __builtin_amdgcn_s_setprio(0);

        // ---- per-lane online softmax (2 shuffle steps across kg groups)
        float pmax = -1e30f;
        #pragma unroll
        for (int n = 0; n < 4; ++n)
            #pragma unroll
            for (int j = 0; j < 4; ++j) pmax = fmaxf(pmax, s[n][j]);
        pmax = fmaxf(pmax, __shfl_xor(pmax, 16, 64));
        pmax = fmaxf(pmax, __shfl_xor(pmax, 32, 64));

        if (!__all(pmax <= m_run + 8.0f)) {   // defer-max (exact)
            const float mn   = fmaxf(m_run, pmax);
            const float corr = __expf(m_run - mn);
            m_run = mn;
            l_run *= corr;
            #pragma unroll
            for (int nd = 0; nd < 4; ++nd)
                #pragma unroll
                for (int j = 0; j < 4; ++j) o_acc[nd][j] *= corr;
        }

        float rs = 0.f;
        #pragma unroll
        for (int n = 0; n < 4; ++n)
            #pragma unroll
            for (int j = 0; j < 4; ++j) {
                const float e = __expf(s[n][j] - m_run);
                s[n][j] = e; rs += e;
            }
        rs += __shfl_xor(rs, 16, 64);
        rs += __shfl_xor(rs, 32, 64);
        l_run += rs;

        // ---- P -> LDS row-major (b64 writes, 2-way free)
        #pragma unroll
        for (int n = 0; n < 4; ++n) {
            bf16x4 pw;
            #pragma unroll
            for (int j = 0; j < 4; ++j) pw[j] = (bf16)s[n][j];
            *(bf16x4*)&Ps[w][lr][n * 16 + kg * 4] = pw;
        }

        // ---- O^T += V^T · P  (A = V^T frag, B = P frag)
        const bf16x8 pf0 = *(const bf16x8*)&Ps[w][lr][kg * 8];
        const bf16x8 pf1 = *(const bf16x8*)&Ps[w][lr][32 + kg * 8];
        __builtin_amdgcn_s_setprio(1);
        #pragma unroll
        for (int nd = 0; nd < 4; ++nd) {
            const int d   = nd * 16 + lr;
            const int keyv = (d ^ (d >> 3)) & 7;
            const bf16x8 vf0 = *(const bf16x8*)((const char*)&Vt[cur][d][0] + ((kg ^ keyv) << 4));
            const bf16x8 vf1 = *(const bf16x8*)((const char*)&Vt[cur][d][0] + (((4 + kg) ^ keyv) << 4));
            o_acc[nd] = __builtin_amdgcn_mfma_f32_16x16x32_bf16(vf0, pf0, o_acc[nd], 0, 0, 0);
            o_acc[nd] = __builtin_amdgcn_mfma_f32_16x16x32_bf16(vf1, pf1, o_acc[nd], 0, 0, 0);
        }
        __builtin_amdgcn_s_setprio(0);

        if (more) storeKV(cur ^ 1);           // write late
        __syncthreads();
        cur ^= 1;
    }

    // ---- finalize: O[q][d], q = q0+w*16+lr, d = nd*16+kg*4+j
    const float inv = 1.0f / l_run;
    bf16* ob = od + (size_t)(b * SEQ + q0 + w * 16 + lr) * DIM + h * 64;
    #pragma unroll
    for (int nd = 0; nd < 4; ++nd) {
        bf16x4 o4;
        #pragma unroll
        for (int j = 0; j < 4; ++j) o4[j] = (bf16)(o_acc[nd][j] * inv);
        *(bf16x4*)(ob + nd * 16 + kg * 4) = o4;
    }
}

// ---------------------------------------------------------------- launch
extern "C" void kernel_launch(void* const* d_in, const int* in_sizes, int n_in,
                              void* d_out, int out_size, void* d_ws, size_t ws_size,
                              hipStream_t stream)
{
    const float* x    = (const float*)d_in[0];
    const float* ln1w = (const float*)d_in[1];
    const float* ln1b = (const float*)d_in[2];
    const float* Wq   = (const float*)d_in[3];
    const float* Wk   = (const float*)d_in[4];
    const float* Wv   = (const float*)d_in[5];
    const float* Wo   = (const float*)d_in[6];
    const float* bo   = (const float*)d_in[7];
    const float* ln2w = (const float*)d_in[8];
    const float* ln2b = (const float*)d_in[9];
    const float* W1   = (const float*)d_in[10];
    const float* b1   = (const float*)d_in[11];
    const float* W2   = (const float*)d_in[12];
    const float* b2   = (const float*)d_in[13];

    char* ws = (char*)d_ws;
    float* xbuf  = (float*)(ws);                 // 8 MB f32 residual
    bf16*  hbuf  = (bf16*)(ws + (8ull  << 20));  // 4 MB
    bf16*  qkvb  = (bf16*)(ws + (12ull << 20));  // 12 MB
    bf16*  obuf  = (bf16*)(ws + (24ull << 20));  // 4 MB
    bf16*  gbuf  = (bf16*)(ws + (28ull << 20));  // 16 MB
    bf16*  wqkvt = (bf16*)(ws + (44ull << 20));  // 6 MB  [3072][1024]
    bf16*  wot   = (bf16*)(ws + (50ull << 20));  // 2 MB  [1024][1024]
    bf16*  w1t   = (bf16*)(ws + (52ull << 20));  // 8 MB  [4096][1024]
    bf16*  w2t   = (bf16*)(ws + (60ull << 20));  // 8 MB  [1024][4096]
    float* pbuf  = (float*)(ws + (68ull << 20)); // 16 MB [2][TOK][DIM] f32

    hipMemcpyAsync(xbuf, x, (size_t)TOK * DIM * sizeof(float),
                   hipMemcpyDeviceToDevice, stream);

    const size_t DD = (size_t)DIM * DIM, DF = (size_t)DIM * FF;
    for (int l = 0; l < LAYERS; ++l) {
        wtrans_all_kernel<<<12288, 256, 0, stream>>>(
            Wq + l * DD, Wk + l * DD, Wv + l * DD, Wo + l * DD,
            W1 + l * DF, W2 + l * DF, wqkvt, wot, w1t, w2t);

        if (l == 0)
            ln_kernel<<<TOK, 256, 0, stream>>>(xbuf, ln1w, ln1b, hbuf);

        gemm_kernel<0, 1><<<16 * 48, 256, 0, stream>>>(
            hbuf, wqkvt, nullptr, qkvb, TOK, QKVN, DIM);

        attn_kernel<<<512, 256, 0, stream>>>(qkvb, obuf);

        gemm_kernel<3, 2><<<16 * 16 * 2, 256, 0, stream>>>(
            obuf, wot, nullptr, pbuf, TOK, DIM, DIM);

        lncomb_kernel<true><<<TOK, 256, 0, stream>>>(
            xbuf, pbuf, bo + l * DIM, ln2w + l * DIM, ln2b + l * DIM, hbuf);

        gemm_kernel<1, 1><<<16 * 64, 256, 0, stream>>>(
            hbuf, w1t, b1 + l * FF, gbuf, TOK, FF, DIM);

        gemm_kernel<3, 2><<<16 * 16 * 2, 256, 0, stream>>>(
            gbuf, w2t, nullptr, pbuf, TOK, DIM, FF);

        if (l + 1 < LAYERS)
            lncomb_kernel<true><<<TOK, 256, 0, stream>>>(
                xbuf, pbuf, b2 + l * DIM, ln1w + (l + 1) * DIM, ln1b + (l + 1) * DIM, hbuf);
        else
            lncomb_kernel<false><<<TOK, 256, 0, stream>>>(
                xbuf, pbuf, b2 + l * DIM, nullptr, nullptr, nullptr);
    }

    hipMemcpyAsync(d_out, xbuf, (size_t)TOK * DIM * sizeof(float),
                   hipMemcpyDeviceToDevice, stream);
}